// Round 13
// baseline (224.502 us; speedup 1.0000x reference)
//
#include <hip/hip_runtime.h>
#include <hip/hip_bf16.h>

#define B_DIM 64
#define T_DIM 512
#define H_DIM 1024

typedef __attribute__((ext_vector_type(4))) float f32x4;

// ws layout (bytes)
#define AQ8_OFF  0UL              // A fp8 frag-major: 32768*1024 = 33554432
#define BQ8_OFF  33554432UL       // W fp8 frag-major: 1024*1024  =  1048576
#define DEC_OFF  34603008UL       // 64*1024*4  =  262144
#define PART_OFF 34865152UL       // 32768*8*4  = 1048576
#define AT_OFF   35913728UL       // 32768*4    =  131072
// total 36044800 bytes

// ---- fp8 e4m3fn: HW packed encode; software decode (OCP-consistent) ----
__device__ __forceinline__ unsigned cvt4_fp8(float a, float b, float c, float d) {
  unsigned r = 0;
  r = __builtin_amdgcn_cvt_pk_fp8_f32(a, b, r, false);   // bytes 0,1
  r = __builtin_amdgcn_cvt_pk_fp8_f32(c, d, r, true);    // bytes 2,3
  return r;
}
__device__ __forceinline__ float e4m3f(unsigned char v) {
  unsigned e = (v >> 3) & 15u, m = v & 7u;
  float mag = (e == 0) ? (float)m * 0.001953125f
                       : (float)(8 + m) * __uint_as_float((e + 117u) << 23);
  return (v & 0x80u) ? -mag : mag;
}

__device__ __forceinline__ void gload_lds16(const void* g, void* l) {
  __builtin_amdgcn_global_load_lds(
      (const __attribute__((address_space(1))) void*)g,
      (__attribute__((address_space(3))) void*)l, 16, 0, 0);
}

// Fragment-major fp8 layout (16x16x32 MFMA frags):
// frag(mt,kt) = 512B at ((mt*32)+kt)*512; lane l holds X[row=mt*16+(l&15)]
// [k = kt*32 + (l>>4)*8 + j], j=0..7.

// K1: conv-only prep — fp32 -> fp8 frag-major (HW cvt); NO copy stream.
// blocks 0..2047: A m-tiles. 2048..2111: W n-tiles. 2112: s_t tail... tail
// moved to score; block 2112 unused-guard removed (grid 2112).
__global__ __launch_bounds__(256) void prep_ws(
    const float* __restrict__ prev,
    const float* __restrict__ Wp,
    unsigned char* __restrict__ Aq,
    unsigned char* __restrict__ Wq) {
  __shared__ unsigned char lq[2][16][528];   // 528 = 512 + 16 pad
  int bid = blockIdx.x;
  int tid = threadIdx.x;

  bool isA = bid < 2048;
  int mt = isA ? bid : bid - 2048;
  const float4* src4 = (const float4*)(isA ? prev : Wp) + (size_t)mt * 4096;
  unsigned char* q8 = (isA ? Aq : Wq) + (size_t)mt * 16384;  // 32 frags
  float scale = isA ? 4.f : 16.f;

  float4 buf[8];
  // ---- issue all 8 loads of half 0 ----
  #pragma unroll
  for (int p = 0; p < 8; p++) {
    int idx = p * 256 + tid;
    int r = idx >> 7, cg = idx & 127;
    buf[p] = src4[(size_t)r * 256 + cg];
  }
  // ---- consume half 0: HW fp8 -> LDS[0] ----
  #pragma unroll
  for (int p = 0; p < 8; p++) {
    int idx = p * 256 + tid;
    int r = idx >> 7, cg = idx & 127;
    *(unsigned*)&lq[0][r][cg * 4] =
        cvt4_fp8(buf[p].x * scale, buf[p].y * scale,
                 buf[p].z * scale, buf[p].w * scale);
  }
  // ---- issue all 8 loads of half 1 (in flight across barrier) ----
  #pragma unroll
  for (int p = 0; p < 8; p++) {
    int idx = p * 256 + tid;
    int r = idx >> 7, cg = idx & 127;
    buf[p] = src4[(size_t)r * 256 + 128 + cg];
  }
  asm volatile("s_waitcnt lgkmcnt(0)" ::: "memory");
  __builtin_amdgcn_s_barrier();

  // ---- gather half 0: frag-major stores (contiguous 16B/thread) ----
  #pragma unroll
  for (int cc = 0; cc < 2; cc++) {
    int c = cc * 256 + tid;          // 0..511
    int ktl = c >> 5, ci = c & 31;
    int r0 = (2 * ci) & 15, oct = ci >> 3;
    uint2 lo = *(const uint2*)&lq[0][r0][ktl * 32 + oct * 8];
    uint2 hi = *(const uint2*)&lq[0][r0 + 1][ktl * 32 + oct * 8];
    uint4 val = make_uint4(lo.x, lo.y, hi.x, hi.y);
    *(uint4*)(q8 + (size_t)ktl * 512 + ci * 16) = val;
  }
  // ---- consume half 1: HW fp8 -> LDS[1] ----
  #pragma unroll
  for (int p = 0; p < 8; p++) {
    int idx = p * 256 + tid;
    int r = idx >> 7, cg = idx & 127;
    *(unsigned*)&lq[1][r][cg * 4] =
        cvt4_fp8(buf[p].x * scale, buf[p].y * scale,
                 buf[p].z * scale, buf[p].w * scale);
  }
  asm volatile("s_waitcnt lgkmcnt(0)" ::: "memory");
  __builtin_amdgcn_s_barrier();

  // ---- gather half 1 (kt 16..31) ----
  #pragma unroll
  for (int cc = 0; cc < 2; cc++) {
    int c = cc * 256 + tid;
    int ktl = c >> 5, ci = c & 31;
    int r0 = (2 * ci) & 15, oct = ci >> 3;
    uint2 lo = *(const uint2*)&lq[1][r0][ktl * 32 + oct * 8];
    uint2 hi = *(const uint2*)&lq[1][r0 + 1][ktl * 32 + oct * 8];
    uint4 val = make_uint4(lo.x, lo.y, hi.x, hi.y);
    *(uint4*)(q8 + (size_t)(16 + ktl) * 512 + ci * 16) = val;
  }
}

// K2: dec_fea[b][o] = sum_h s_t[b][h]*W_s[o][h] + b_s[o]
__global__ void dec_kernel(const float* __restrict__ st,
                           const float* __restrict__ Ws,
                           const float* __restrict__ bs,
                           float* __restrict__ dec) {
  int tid = threadIdx.x;
  int lane = tid & 63, w = tid >> 6;
  int o = blockIdx.x * 4 + w;
  const float4* wrow = (const float4*)(Ws + (size_t)o * H_DIM);
  float4 w0 = wrow[lane], w1 = wrow[64 + lane], w2 = wrow[128 + lane], w3 = wrow[192 + lane];
  const float4* st4 = (const float4*)st;
  float bias = bs[o];
  #pragma unroll 8
  for (int b = 0; b < B_DIM; b++) {
    const float4* s = st4 + (size_t)b * 256;
    float4 s0 = s[lane], s1 = s[64 + lane], s2 = s[128 + lane], s3 = s[192 + lane];
    float p = w0.x * s0.x + w0.y * s0.y + w0.z * s0.z + w0.w * s0.w
            + w1.x * s1.x + w1.y * s1.y + w1.z * s1.z + w1.w * s1.w
            + w2.x * s2.x + w2.y * s2.y + w2.z * s2.z + w2.w * s2.w
            + w3.x * s3.x + w3.y * s3.y + w3.z * s3.z + w3.w * s3.w;
    p += __shfl_xor(p, 1);  p += __shfl_xor(p, 2);
    p += __shfl_xor(p, 4);  p += __shfl_xor(p, 8);
    p += __shfl_xor(p, 16); p += __shfl_xor(p, 32);
    if (lane == 0) dec[(size_t)b * H_DIM + o] = p + bias;
  }
}

// K3: fp8 score GEMM + FUSED concat copy (uses score's idle memory pipe).
// GEMM: 128x128 block, 2x2 waves of 64x64, BK=64, frag-major LDS,
// raw-barrier + counted-vmcnt(4). acc = 64*et.
// Copy: block (bm,bn) copies prev rows [bm*128+bn*16, +16) -> out concat;
// blocks swz<64 copy s_t tail row swz. Woven around tanh epilogue.
__global__ __launch_bounds__(256, 3) void score_gemm(
    const unsigned char* __restrict__ Aq,
    const unsigned char* __restrict__ Bq,
    const float* __restrict__ dec,
    const float* __restrict__ v,
    const float* __restrict__ prev,
    const float* __restrict__ st,
    float* __restrict__ out,
    float* __restrict__ part)
{
  __shared__ __align__(16) unsigned char ldsA[2][8192];
  __shared__ __align__(16) unsigned char ldsB[2][8192];

  int orig = blockIdx.x;                       // 2048 blocks
  int swz = (orig & 7) * 256 + (orig >> 3);    // bijective XCD swizzle
  int bm = swz >> 3, bn = swz & 7;

  int tid = threadIdx.x;
  int lane = tid & 63, w = tid >> 6;
  int wm = w >> 1, wn = w & 1;                 // 2x2 waves, 64x64 each
  size_t m0 = (size_t)bm * 128;

  f32x4 acc[4][4];
  #pragma unroll
  for (int i = 0; i < 4; i++)
    #pragma unroll
    for (int j = 0; j < 4; j++) {
      f32x4 z; z.x = 0.f; z.y = 0.f; z.z = 0.f; z.w = 0.f;
      acc[i][j] = z;
    }

  int fA = tid >> 5, cif = tid & 31;
  const unsigned char* aSrc0 =
      Aq + ((size_t)(bm * 8 + (fA >> 1)) * 32 + (fA & 1)) * 512 + (size_t)cif * 16;
  const unsigned char* aSrc1 =
      Aq + ((size_t)(bm * 8 + (fA >> 1) + 4) * 32 + (fA & 1)) * 512 + (size_t)cif * 16;
  const unsigned char* bSrc0 =
      Bq + ((size_t)(bn * 8 + (fA >> 1)) * 32 + (fA & 1)) * 512 + (size_t)cif * 16;
  const unsigned char* bSrc1 =
      Bq + ((size_t)(bn * 8 + (fA >> 1) + 4) * 32 + (fA & 1)) * 512 + (size_t)cif * 16;

#define STAGE(buf, t) do { \
    size_t ko = (size_t)(t) * 1024; \
    gload_lds16(aSrc0 + ko, &ldsA[(buf)][tid * 16]); \
    gload_lds16(aSrc1 + ko, &ldsA[(buf)][tid * 16 + 4096]); \
    gload_lds16(bSrc0 + ko, &ldsB[(buf)][tid * 16]); \
    gload_lds16(bSrc1 + ko, &ldsB[(buf)][tid * 16 + 4096]); \
  } while (0)

  STAGE(0, 0);

  #pragma unroll 2
  for (int t = 0; t < 16; t++) {
    int cur = t & 1, nxt = cur ^ 1;
    if (t < 15) {
      STAGE(nxt, t + 1);
      asm volatile("s_waitcnt vmcnt(4)" ::: "memory");
    } else {
      asm volatile("s_waitcnt vmcnt(0)" ::: "memory");
    }
    __builtin_amdgcn_s_barrier();
    asm volatile("" ::: "memory");

    const unsigned char* Ac = &ldsA[cur][0];
    const unsigned char* Bc = &ldsB[cur][0];
    long av[4][2], bv[4][2];
    #pragma unroll
    for (int mf = 0; mf < 4; mf++)
      #pragma unroll
      for (int kk = 0; kk < 2; kk++)
        av[mf][kk] = *(const long*)(Ac + ((wm * 4 + mf) * 2 + kk) * 512 + lane * 8);
    #pragma unroll
    for (int nf = 0; nf < 4; nf++)
      #pragma unroll
      for (int kk = 0; kk < 2; kk++)
        bv[nf][kk] = *(const long*)(Bc + ((wn * 4 + nf) * 2 + kk) * 512 + lane * 8);

    __builtin_amdgcn_s_setprio(1);
    #pragma unroll
    for (int kk = 0; kk < 2; kk++)
      #pragma unroll
      for (int mf = 0; mf < 4; mf++)
        #pragma unroll
        for (int nf = 0; nf < 4; nf++)
          acc[mf][nf] = __builtin_amdgcn_mfma_f32_16x16x32_fp8_fp8(
              av[mf][kk], bv[nf][kk], acc[mf][nf], 0, 0, 0);
    __builtin_amdgcn_s_setprio(0);
    asm volatile("" ::: "memory");
    __builtin_amdgcn_s_barrier();
  }
#undef STAGE

  // ---- fused copy setup: this block's 16 rows ----
  int crow0 = (int)m0 + bn * 16;
  int cb = crow0 >> 9;
  int ct0 = crow0 & 511;
  const float4* csrc = (const float4*)prev + (size_t)crow0 * 256;
  float4* cdst = (float4*)out + 16384 + (size_t)cb * 131328 + (size_t)ct0 * 256;
  float4 cbuf[8];
  #pragma unroll
  for (int i = 0; i < 8; i++) cbuf[i] = csrc[i * 256 + tid];   // rows 0..7

  // epilogue: x = acc/64 + dec; tanh; dot v; 16-col shfl reduce; wn-pair via LDS
  int b = (int)(m0 >> 9);
  int lr = lane >> 4, lc = lane & 15;
  int n0 = bn * 128;
  float dv[4], vv[4];
  #pragma unroll
  for (int nf = 0; nf < 4; nf++) {
    int col = n0 + wn * 64 + nf * 16 + lc;
    dv[nf] = dec[(size_t)b * H_DIM + col];
    vv[nf] = v[col];
  }
  float* epi = (float*)&ldsA[0][0];  // [128 rows][2 wn] floats = 1KB
  #pragma unroll
  for (int mf = 0; mf < 4; mf++) {
    #pragma unroll
    for (int r = 0; r < 4; r++) {
      float s = 0.f;
      #pragma unroll
      for (int nf = 0; nf < 4; nf++) {
        float x = acc[mf][nf][r] * 0.015625f + dv[nf];
        x = fminf(fmaxf(x, -15.f), 15.f);
        float e = __expf(2.f * x);
        s += vv[nf] * (e - 1.f) * __builtin_amdgcn_rcpf(e + 1.f);
      }
      s += __shfl_xor(s, 1); s += __shfl_xor(s, 2);
      s += __shfl_xor(s, 4); s += __shfl_xor(s, 8);
      if (lc == 0) epi[(wm * 64 + mf * 16 + lr * 4 + r) * 2 + wn] = s;
    }
  }
  // copy batch 1 stores (loads covered by epilogue VALU), batch 2 loads
  #pragma unroll
  for (int i = 0; i < 8; i++) cdst[i * 256 + tid] = cbuf[i];
  #pragma unroll
  for (int i = 0; i < 8; i++) cbuf[i] = csrc[(8 + i) * 256 + tid]; // rows 8..15
  __syncthreads();
  if (tid < 128) {
    part[(m0 + tid) * 8 + bn] = epi[tid * 2] + epi[tid * 2 + 1];
  }
  #pragma unroll
  for (int i = 0; i < 8; i++) cdst[(8 + i) * 256 + tid] = cbuf[i];
  // tail: blocks swz<64 copy s_t row swz into the concat tail
  if (swz < 64) {
    ((float4*)out)[16384 + (size_t)swz * 131328 + 131072 + tid] =
        ((const float4*)st)[(size_t)swz * 256 + tid];
  }
}

// K4: softmax over T per batch row (8 partials per row)
__global__ void softmax_kernel(const float* __restrict__ part, float* __restrict__ at) {
  int b = blockIdx.x, tid = threadIdx.x;
  __shared__ float sc[512];
  __shared__ float red[8];
  #pragma unroll
  for (int rep = 0; rep < 2; rep++) {
    int t = rep * 256 + tid;
    const float* p = part + ((size_t)b * 512 + t) * 8;
    sc[t] = p[0] + p[1] + p[2] + p[3] + p[4] + p[5] + p[6] + p[7];
  }
  __syncthreads();
  float m = fmaxf(sc[tid], sc[tid + 256]);
  for (int d = 1; d < 64; d <<= 1) m = fmaxf(m, __shfl_xor(m, d));
  if ((tid & 63) == 0) red[tid >> 6] = m;
  __syncthreads();
  m = fmaxf(fmaxf(red[0], red[1]), fmaxf(red[2], red[3]));
  float e0 = __expf(sc[tid] - m), e1 = __expf(sc[tid + 256] - m);
  float s = e0 + e1;
  for (int d = 1; d < 64; d <<= 1) s += __shfl_xor(s, d);
  if ((tid & 63) == 0) red[4 + (tid >> 6)] = s;
  __syncthreads();
  s = red[4] + red[5] + red[6] + red[7];
  float inv = 1.f / s;
  at[(size_t)b * 512 + tid] = e0 * inv;
  at[(size_t)b * 512 + tid + 256] = e1 * inv;
}

// K5: ct_d[b][h] = sum_t at[b][t] * prev[b][t][h] from fp8 frag-major A'
// (values are 4x -> scale 0.25). One wave per (b, kt): in-wave reduction.
__global__ void ctd_ws(const unsigned char* __restrict__ Aq,
                       const float* __restrict__ at, float* __restrict__ out) {
  int wid = blockIdx.x * 4 + (threadIdx.x >> 6);  // 2048 = 64 b x 32 kt
  int lane = threadIdx.x & 63;
  int b = wid >> 5, kt = wid & 31;
  int lc = lane & 15, lr = lane >> 4;
  float a8[8] = {0.f, 0.f, 0.f, 0.f, 0.f, 0.f, 0.f, 0.f};
  const unsigned char* base =
      Aq + ((size_t)b * 32 * 32 + kt) * 512 + (size_t)lane * 8;
  const float* atb = at + (size_t)b * 512;
  #pragma unroll 8
  for (int mt = 0; mt < 32; mt++) {
    float a = atb[mt * 16 + lc];
    uint2 uv = *(const uint2*)(base + (size_t)mt * 16384);
    unsigned char* q = (unsigned char*)&uv;
    #pragma unroll
    for (int j = 0; j < 8; j++) a8[j] += a * e4m3f(q[j]);
  }
  #pragma unroll
  for (int d = 1; d < 16; d <<= 1)
    #pragma unroll
    for (int j = 0; j < 8; j++) a8[j] += __shfl_xor(a8[j], d);
  if (lc == 0) {
    #pragma unroll
    for (int j = 0; j < 8; j++)
      out[(size_t)b * H_DIM + kt * 32 + lr * 8 + j] = a8[j] * 0.25f;
  }
}

extern "C" void kernel_launch(void* const* d_in, const int* in_sizes, int n_in,
                              void* d_out, int out_size, void* d_ws, size_t ws_size,
                              hipStream_t stream) {
  (void)in_sizes; (void)n_in; (void)out_size; (void)ws_size;
  const float* s_t    = (const float*)d_in[0];
  const float* prev_s = (const float*)d_in[1];
  const float* W_prev = (const float*)d_in[2];
  const float* W_s    = (const float*)d_in[3];
  const float* b_s    = (const float*)d_in[4];
  const float* v      = (const float*)d_in[5];
  float* out = (float*)d_out;
  char* ws = (char*)d_ws;

  unsigned char* Aq = (unsigned char*)(ws + AQ8_OFF);
  unsigned char* Wq = (unsigned char*)(ws + BQ8_OFF);
  float* dec  = (float*)(ws + DEC_OFF);
  float* part = (float*)(ws + PART_OFF);
  float* at   = (float*)(ws + AT_OFF);

  prep_ws<<<2112, 256, 0, stream>>>(prev_s, W_prev, Aq, Wq);
  dec_kernel<<<256, 256, 0, stream>>>(s_t, W_s, b_s, dec);
  score_gemm<<<2048, 256, 0, stream>>>(Aq, Wq, dec, v, prev_s, s_t, out, part);
  softmax_kernel<<<64, 256, 0, stream>>>(part, at);
  ctd_ws<<<512, 256, 0, stream>>>(Aq, at, out);
}

// Round 15
// 165.338 us; speedup vs baseline: 1.3578x; 1.3578x over previous
//
#include <hip/hip_runtime.h>
#include <hip/hip_bf16.h>

#define B_DIM 64
#define T_DIM 512
#define H_DIM 1024

typedef __attribute__((ext_vector_type(4))) float f32x4;

// ws layout (bytes)
#define AQ8_OFF  0UL              // A fp8 frag-major: 32768*1024 = 33554432
#define BQ8_OFF  33554432UL       // W fp8 frag-major: 1024*1024  =  1048576
#define DEC_OFF  34603008UL       // 64*1024*4  =  262144
#define PART_OFF 34865152UL       // 32768*8*4  = 1048576
#define AT_OFF   35913728UL       // 32768*4    =  131072
// total 36044800 bytes

// ---- fp8 e4m3fn: HW packed encode + HW decode ----
__device__ __forceinline__ unsigned cvt4_fp8(float a, float b, float c, float d) {
  unsigned r = 0;
  r = __builtin_amdgcn_cvt_pk_fp8_f32(a, b, r, false);   // bytes 0,1
  r = __builtin_amdgcn_cvt_pk_fp8_f32(c, d, r, true);    // bytes 2,3
  return r;
}

__device__ __forceinline__ void gload_lds16(const void* g, void* l) {
  __builtin_amdgcn_global_load_lds(
      (const __attribute__((address_space(1))) void*)g,
      (__attribute__((address_space(3))) void*)l, 16, 0, 0);
}

// Fragment-major fp8 layout (16x16x32 MFMA frags):
// frag(mt,kt) = 512B at ((mt*32)+kt)*512; lane l holds X[row=mt*16+(l&15)]
// [k = kt*32 + (l>>4)*8 + j], j=0..7.

// K1: fused prep — read prev once; write fp32 concat copy (NONTEMPORAL,
// via native ext-vector f32x4) + fp8 frag-major (cached); HW cvt encode;
// deep-ILP loads; ping-pong LDS transpose; 2 raw barriers.
// blocks 0..2047: A. 2048..2111: W. 2112: s_t tail.
__global__ __launch_bounds__(256) void prep_ws(
    const float* __restrict__ prev,
    const float* __restrict__ st,
    const float* __restrict__ Wp,
    float* __restrict__ out,
    unsigned char* __restrict__ Aq,
    unsigned char* __restrict__ Wq) {
  __shared__ unsigned char lq[2][16][528];   // 528 = 512 + 16 pad
  int bid = blockIdx.x;
  int tid = threadIdx.x;

  if (bid < 2112) {
    bool isA = bid < 2048;
    int mt = isA ? bid : bid - 2048;
    const f32x4* src4 = (const f32x4*)(isA ? prev : Wp) + (size_t)mt * 4096;
    f32x4* dst4 = nullptr;
    if (isA) {
      int b = mt >> 5, t0 = (mt & 31) * 16;
      dst4 = (f32x4*)out + 16384 + (size_t)b * 131328 + (size_t)t0 * 256;
    }
    unsigned char* q8 = (isA ? Aq : Wq) + (size_t)mt * 16384;  // 32 frags
    float scale = isA ? 4.f : 16.f;

    f32x4 buf[8];
    // ---- issue all 8 loads of half 0 ----
    #pragma unroll
    for (int p = 0; p < 8; p++) {
      int idx = p * 256 + tid;
      int r = idx >> 7, cg = idx & 127;
      buf[p] = src4[(size_t)r * 256 + cg];
    }
    // ---- consume half 0: NT copy write + HW fp8 -> LDS[0] ----
    #pragma unroll
    for (int p = 0; p < 8; p++) {
      int idx = p * 256 + tid;
      int r = idx >> 7, cg = idx & 127;
      if (isA) __builtin_nontemporal_store(buf[p], &dst4[(size_t)r * 256 + cg]);
      *(unsigned*)&lq[0][r][cg * 4] =
          cvt4_fp8(buf[p][0] * scale, buf[p][1] * scale,
                   buf[p][2] * scale, buf[p][3] * scale);
    }
    // ---- issue all 8 loads of half 1 (in flight across barrier) ----
    #pragma unroll
    for (int p = 0; p < 8; p++) {
      int idx = p * 256 + tid;
      int r = idx >> 7, cg = idx & 127;
      buf[p] = src4[(size_t)r * 256 + 128 + cg];
    }
    asm volatile("s_waitcnt lgkmcnt(0)" ::: "memory");
    __builtin_amdgcn_s_barrier();

    // ---- gather half 0: frag-major stores (contiguous 16B/thread) ----
    #pragma unroll
    for (int cc = 0; cc < 2; cc++) {
      int c = cc * 256 + tid;          // 0..511
      int ktl = c >> 5, ci = c & 31;
      int r0 = (2 * ci) & 15, oct = ci >> 3;
      uint2 lo = *(const uint2*)&lq[0][r0][ktl * 32 + oct * 8];
      uint2 hi = *(const uint2*)&lq[0][r0 + 1][ktl * 32 + oct * 8];
      uint4 val = make_uint4(lo.x, lo.y, hi.x, hi.y);
      *(uint4*)(q8 + (size_t)ktl * 512 + ci * 16) = val;
    }
    // ---- consume half 1: NT copy write + HW fp8 -> LDS[1] ----
    #pragma unroll
    for (int p = 0; p < 8; p++) {
      int idx = p * 256 + tid;
      int r = idx >> 7, cg = idx & 127;
      if (isA) __builtin_nontemporal_store(buf[p], &dst4[(size_t)r * 256 + 128 + cg]);
      *(unsigned*)&lq[1][r][cg * 4] =
          cvt4_fp8(buf[p][0] * scale, buf[p][1] * scale,
                   buf[p][2] * scale, buf[p][3] * scale);
    }
    asm volatile("s_waitcnt lgkmcnt(0)" ::: "memory");
    __builtin_amdgcn_s_barrier();

    // ---- gather half 1 (kt 16..31) ----
    #pragma unroll
    for (int cc = 0; cc < 2; cc++) {
      int c = cc * 256 + tid;
      int ktl = c >> 5, ci = c & 31;
      int r0 = (2 * ci) & 15, oct = ci >> 3;
      uint2 lo = *(const uint2*)&lq[1][r0][ktl * 32 + oct * 8];
      uint2 hi = *(const uint2*)&lq[1][r0 + 1][ktl * 32 + oct * 8];
      uint4 val = make_uint4(lo.x, lo.y, hi.x, hi.y);
      *(uint4*)(q8 + (size_t)(16 + ktl) * 512 + ci * 16) = val;
    }
  } else {                                // ---- s_t tail rows ----
    const f32x4* s4 = (const f32x4*)st;
    for (int b = 0; b < B_DIM; b++) {
      f32x4* o4 = (f32x4*)out + 16384 + (size_t)b * 131328 + 131072;
      __builtin_nontemporal_store(s4[(size_t)b * 256 + tid], &o4[tid]);
    }
  }
}

// K2: dec_fea[b][o] = sum_h s_t[b][h]*W_s[o][h] + b_s[o]
__global__ void dec_kernel(const float* __restrict__ st,
                           const float* __restrict__ Ws,
                           const float* __restrict__ bs,
                           float* __restrict__ dec) {
  int tid = threadIdx.x;
  int lane = tid & 63, w = tid >> 6;
  int o = blockIdx.x * 4 + w;
  const float4* wrow = (const float4*)(Ws + (size_t)o * H_DIM);
  float4 w0 = wrow[lane], w1 = wrow[64 + lane], w2 = wrow[128 + lane], w3 = wrow[192 + lane];
  const float4* st4 = (const float4*)st;
  float bias = bs[o];
  #pragma unroll 8
  for (int b = 0; b < B_DIM; b++) {
    const float4* s = st4 + (size_t)b * 256;
    float4 s0 = s[lane], s1 = s[64 + lane], s2 = s[128 + lane], s3 = s[192 + lane];
    float p = w0.x * s0.x + w0.y * s0.y + w0.z * s0.z + w0.w * s0.w
            + w1.x * s1.x + w1.y * s1.y + w1.z * s1.z + w1.w * s1.w
            + w2.x * s2.x + w2.y * s2.y + w2.z * s2.z + w2.w * s2.w
            + w3.x * s3.x + w3.y * s3.y + w3.z * s3.z + w3.w * s3.w;
    p += __shfl_xor(p, 1);  p += __shfl_xor(p, 2);
    p += __shfl_xor(p, 4);  p += __shfl_xor(p, 8);
    p += __shfl_xor(p, 16); p += __shfl_xor(p, 32);
    if (lane == 0) dec[(size_t)b * H_DIM + o] = p + bias;
  }
}

// K3: fp8 score GEMM. 128x128 block, 2x2 waves of 64x64, BK=64,
// fragment-major LDS (linear stage, conflict-free ds_read_b64),
// raw-barrier + counted-vmcnt(4). acc = 64*et.
__global__ __launch_bounds__(256, 3) void score_gemm(
    const unsigned char* __restrict__ Aq,
    const unsigned char* __restrict__ Bq,
    const float* __restrict__ dec,
    const float* __restrict__ v,
    float* __restrict__ part)
{
  __shared__ __align__(16) unsigned char ldsA[2][8192];
  __shared__ __align__(16) unsigned char ldsB[2][8192];

  int orig = blockIdx.x;                       // 2048 blocks
  int swz = (orig & 7) * 256 + (orig >> 3);    // bijective XCD swizzle
  int bm = swz >> 3, bn = swz & 7;

  int tid = threadIdx.x;
  int lane = tid & 63, w = tid >> 6;
  int wm = w >> 1, wn = w & 1;                 // 2x2 waves, 64x64 each
  size_t m0 = (size_t)bm * 128;

  f32x4 acc[4][4];
  #pragma unroll
  for (int i = 0; i < 4; i++)
    #pragma unroll
    for (int j = 0; j < 4; j++) {
      f32x4 z; z[0] = 0.f; z[1] = 0.f; z[2] = 0.f; z[3] = 0.f;
      acc[i][j] = z;
    }

  int fA = tid >> 5, cif = tid & 31;
  const unsigned char* aSrc0 =
      Aq + ((size_t)(bm * 8 + (fA >> 1)) * 32 + (fA & 1)) * 512 + (size_t)cif * 16;
  const unsigned char* aSrc1 =
      Aq + ((size_t)(bm * 8 + (fA >> 1) + 4) * 32 + (fA & 1)) * 512 + (size_t)cif * 16;
  const unsigned char* bSrc0 =
      Bq + ((size_t)(bn * 8 + (fA >> 1)) * 32 + (fA & 1)) * 512 + (size_t)cif * 16;
  const unsigned char* bSrc1 =
      Bq + ((size_t)(bn * 8 + (fA >> 1) + 4) * 32 + (fA & 1)) * 512 + (size_t)cif * 16;

#define STAGE(buf, t) do { \
    size_t ko = (size_t)(t) * 1024; \
    gload_lds16(aSrc0 + ko, &ldsA[(buf)][tid * 16]); \
    gload_lds16(aSrc1 + ko, &ldsA[(buf)][tid * 16 + 4096]); \
    gload_lds16(bSrc0 + ko, &ldsB[(buf)][tid * 16]); \
    gload_lds16(bSrc1 + ko, &ldsB[(buf)][tid * 16 + 4096]); \
  } while (0)

  STAGE(0, 0);

  #pragma unroll 2
  for (int t = 0; t < 16; t++) {
    int cur = t & 1, nxt = cur ^ 1;
    if (t < 15) {
      STAGE(nxt, t + 1);
      asm volatile("s_waitcnt vmcnt(4)" ::: "memory");
    } else {
      asm volatile("s_waitcnt vmcnt(0)" ::: "memory");
    }
    __builtin_amdgcn_s_barrier();
    asm volatile("" ::: "memory");

    const unsigned char* Ac = &ldsA[cur][0];
    const unsigned char* Bc = &ldsB[cur][0];
    long av[4][2], bv[4][2];
    #pragma unroll
    for (int mf = 0; mf < 4; mf++)
      #pragma unroll
      for (int kk = 0; kk < 2; kk++)
        av[mf][kk] = *(const long*)(Ac + ((wm * 4 + mf) * 2 + kk) * 512 + lane * 8);
    #pragma unroll
    for (int nf = 0; nf < 4; nf++)
      #pragma unroll
      for (int kk = 0; kk < 2; kk++)
        bv[nf][kk] = *(const long*)(Bc + ((wn * 4 + nf) * 2 + kk) * 512 + lane * 8);

    __builtin_amdgcn_s_setprio(1);
    #pragma unroll
    for (int kk = 0; kk < 2; kk++)
      #pragma unroll
      for (int mf = 0; mf < 4; mf++)
        #pragma unroll
        for (int nf = 0; nf < 4; nf++)
          acc[mf][nf] = __builtin_amdgcn_mfma_f32_16x16x32_fp8_fp8(
              av[mf][kk], bv[nf][kk], acc[mf][nf], 0, 0, 0);
    __builtin_amdgcn_s_setprio(0);
    asm volatile("" ::: "memory");
    __builtin_amdgcn_s_barrier();
  }
#undef STAGE

  // epilogue: x = acc/64 + dec; tanh; dot v; 16-col shfl reduce; wn-pair via LDS
  int b = (int)(m0 >> 9);
  int lr = lane >> 4, lc = lane & 15;
  int n0 = bn * 128;
  float dv[4], vv[4];
  #pragma unroll
  for (int nf = 0; nf < 4; nf++) {
    int col = n0 + wn * 64 + nf * 16 + lc;
    dv[nf] = dec[(size_t)b * H_DIM + col];
    vv[nf] = v[col];
  }
  float* epi = (float*)&ldsA[0][0];  // [128 rows][2 wn] floats = 1KB
  #pragma unroll
  for (int mf = 0; mf < 4; mf++) {
    #pragma unroll
    for (int r = 0; r < 4; r++) {
      float s = 0.f;
      #pragma unroll
      for (int nf = 0; nf < 4; nf++) {
        float x = acc[mf][nf][r] * 0.015625f + dv[nf];
        x = fminf(fmaxf(x, -15.f), 15.f);
        float e = __expf(2.f * x);
        s += vv[nf] * (e - 1.f) * __builtin_amdgcn_rcpf(e + 1.f);
      }
      s += __shfl_xor(s, 1); s += __shfl_xor(s, 2);
      s += __shfl_xor(s, 4); s += __shfl_xor(s, 8);
      if (lc == 0) epi[(wm * 64 + mf * 16 + lr * 4 + r) * 2 + wn] = s;
    }
  }
  __syncthreads();
  if (tid < 128) {
    part[(m0 + tid) * 8 + bn] = epi[tid * 2] + epi[tid * 2 + 1];
  }
}

// K4: softmax over T per batch row (8 partials per row)
__global__ void softmax_kernel(const float* __restrict__ part, float* __restrict__ at) {
  int b = blockIdx.x, tid = threadIdx.x;
  __shared__ float sc[512];
  __shared__ float red[8];
  #pragma unroll
  for (int rep = 0; rep < 2; rep++) {
    int t = rep * 256 + tid;
    const float* p = part + ((size_t)b * 512 + t) * 8;
    sc[t] = p[0] + p[1] + p[2] + p[3] + p[4] + p[5] + p[6] + p[7];
  }
  __syncthreads();
  float m = fmaxf(sc[tid], sc[tid + 256]);
  for (int d = 1; d < 64; d <<= 1) m = fmaxf(m, __shfl_xor(m, d));
  if ((tid & 63) == 0) red[tid >> 6] = m;
  __syncthreads();
  m = fmaxf(fmaxf(red[0], red[1]), fmaxf(red[2], red[3]));
  float e0 = __expf(sc[tid] - m), e1 = __expf(sc[tid + 256] - m);
  float s = e0 + e1;
  for (int d = 1; d < 64; d <<= 1) s += __shfl_xor(s, d);
  if ((tid & 63) == 0) red[4 + (tid >> 6)] = s;
  __syncthreads();
  s = red[4] + red[5] + red[6] + red[7];
  float inv = 1.f / s;
  at[(size_t)b * 512 + tid] = e0 * inv;
  at[(size_t)b * 512 + tid + 256] = e1 * inv;
}

// K5: ct_d[b][h] = sum_t at[b][t] * prev[b][t][h] from fp8 frag-major A'
// (values are 4x -> scale 0.25). HW v_cvt_f32_fp8 decode (literal sels).
// One wave per (b, kt): in-wave reduction, no atomics.
__global__ void ctd_ws(const unsigned char* __restrict__ Aq,
                       const float* __restrict__ at, float* __restrict__ out) {
  int wid = blockIdx.x * 4 + (threadIdx.x >> 6);  // 2048 = 64 b x 32 kt
  int lane = threadIdx.x & 63;
  int b = wid >> 5, kt = wid & 31;
  int lc = lane & 15, lr = lane >> 4;
  float a8[8] = {0.f, 0.f, 0.f, 0.f, 0.f, 0.f, 0.f, 0.f};
  const unsigned char* base =
      Aq + ((size_t)b * 32 * 32 + kt) * 512 + (size_t)lane * 8;
  const float* atb = at + (size_t)b * 512;
  #pragma unroll 8
  for (int mt = 0; mt < 32; mt++) {
    float a = atb[mt * 16 + lc];
    uint2 uv = *(const uint2*)(base + (size_t)mt * 16384);
    a8[0] += a * __builtin_amdgcn_cvt_f32_fp8(uv.x, 0);
    a8[1] += a * __builtin_amdgcn_cvt_f32_fp8(uv.x, 1);
    a8[2] += a * __builtin_amdgcn_cvt_f32_fp8(uv.x, 2);
    a8[3] += a * __builtin_amdgcn_cvt_f32_fp8(uv.x, 3);
    a8[4] += a * __builtin_amdgcn_cvt_f32_fp8(uv.y, 0);
    a8[5] += a * __builtin_amdgcn_cvt_f32_fp8(uv.y, 1);
    a8[6] += a * __builtin_amdgcn_cvt_f32_fp8(uv.y, 2);
    a8[7] += a * __builtin_amdgcn_cvt_f32_fp8(uv.y, 3);
  }
  #pragma unroll
  for (int d = 1; d < 16; d <<= 1)
    #pragma unroll
    for (int j = 0; j < 8; j++) a8[j] += __shfl_xor(a8[j], d);
  if (lc == 0) {
    #pragma unroll
    for (int j = 0; j < 8; j++)
      out[(size_t)b * H_DIM + kt * 32 + lr * 8 + j] = a8[j] * 0.25f;
  }
}

extern "C" void kernel_launch(void* const* d_in, const int* in_sizes, int n_in,
                              void* d_out, int out_size, void* d_ws, size_t ws_size,
                              hipStream_t stream) {
  (void)in_sizes; (void)n_in; (void)out_size; (void)ws_size;
  const float* s_t    = (const float*)d_in[0];
  const float* prev_s = (const float*)d_in[1];
  const float* W_prev = (const float*)d_in[2];
  const float* W_s    = (const float*)d_in[3];
  const float* b_s    = (const float*)d_in[4];
  const float* v      = (const float*)d_in[5];
  float* out = (float*)d_out;
  char* ws = (char*)d_ws;

  unsigned char* Aq = (unsigned char*)(ws + AQ8_OFF);
  unsigned char* Wq = (unsigned char*)(ws + BQ8_OFF);
  float* dec  = (float*)(ws + DEC_OFF);
  float* part = (float*)(ws + PART_OFF);
  float* at   = (float*)(ws + AT_OFF);

  prep_ws<<<2113, 256, 0, stream>>>(prev_s, s_t, W_prev, out, Aq, Wq);
  dec_kernel<<<256, 256, 0, stream>>>(s_t, W_s, b_s, dec);
  score_gemm<<<2048, 256, 0, stream>>>(Aq, Wq, dec, v, part);
  softmax_kernel<<<64, 256, 0, stream>>>(part, at);
  ctd_ws<<<512, 256, 0, stream>>>(Aq, at, out);
}

// Round 16
// 159.756 us; speedup vs baseline: 1.4053x; 1.0349x over previous
//
#include <hip/hip_runtime.h>
#include <hip/hip_bf16.h>

#define B_DIM 64
#define T_DIM 512
#define H_DIM 1024

typedef __attribute__((ext_vector_type(4))) float f32x4;

// ws layout (bytes)
#define AQ8_OFF  0UL              // A fp8 frag-major: 32768*1024 = 33554432
#define BQ8_OFF  33554432UL       // W fp8 frag-major: 1024*1024  =  1048576
#define DEC_OFF  34603008UL       // 64*1024*4  =  262144
#define PART_OFF 34865152UL       // 32768*8*4  = 1048576
#define AT_OFF   35913728UL       // 32768*4    =  131072
// total 36044800 bytes

// ---- fp8 e4m3fn: HW packed encode + HW decode ----
__device__ __forceinline__ unsigned cvt4_fp8(float a, float b, float c, float d) {
  unsigned r = 0;
  r = __builtin_amdgcn_cvt_pk_fp8_f32(a, b, r, false);   // bytes 0,1
  r = __builtin_amdgcn_cvt_pk_fp8_f32(c, d, r, true);    // bytes 2,3
  return r;
}

__device__ __forceinline__ void gload_lds16(const void* g, void* l) {
  __builtin_amdgcn_global_load_lds(
      (const __attribute__((address_space(1))) void*)g,
      (__attribute__((address_space(3))) void*)l, 16, 0, 0);
}

// Fragment-major fp8 layout (16x16x32 MFMA frags):
// frag(mt,kt) = 512B at ((mt*32)+kt)*512; lane l holds X[row=mt*16+(l&15)]
// [k = kt*32 + (l>>4)*8 + j], j=0..7.

// K1: mega-prep. Heterogeneous grid:
//   bid 0..2047   : A m-tiles — read prev, write fp32 concat copy + fp8 frags
//   bid 2048..2111: W n-tiles — fp8 frags
//   bid 2112..2367: dec blocks — dec_fea = W_s(s_t)+b_s (independent work,
//                   folded here to absorb its serial launch time)
//   bid 2368      : s_t tail rows of concat
__global__ __launch_bounds__(256) void prep_ws(
    const float* __restrict__ prev,
    const float* __restrict__ st,
    const float* __restrict__ Wp,
    const float* __restrict__ Ws,
    const float* __restrict__ bs,
    float* __restrict__ out,
    unsigned char* __restrict__ Aq,
    unsigned char* __restrict__ Wq,
    float* __restrict__ dec) {
  __shared__ unsigned char lq[2][16][528];   // 528 = 512 + 16 pad
  int bid = blockIdx.x;
  int tid = threadIdx.x;

  if (bid < 2112) {
    bool isA = bid < 2048;
    int mt = isA ? bid : bid - 2048;
    const f32x4* src4 = (const f32x4*)(isA ? prev : Wp) + (size_t)mt * 4096;
    f32x4* dst4 = nullptr;
    if (isA) {
      int b = mt >> 5, t0 = (mt & 31) * 16;
      dst4 = (f32x4*)out + 16384 + (size_t)b * 131328 + (size_t)t0 * 256;
    }
    unsigned char* q8 = (isA ? Aq : Wq) + (size_t)mt * 16384;  // 32 frags
    float scale = isA ? 4.f : 16.f;

    f32x4 buf[8];
    // ---- issue all 8 loads of half 0 ----
    #pragma unroll
    for (int p = 0; p < 8; p++) {
      int idx = p * 256 + tid;
      int r = idx >> 7, cg = idx & 127;
      buf[p] = src4[(size_t)r * 256 + cg];
    }
    // ---- consume half 0: copy write + HW fp8 -> LDS[0] ----
    #pragma unroll
    for (int p = 0; p < 8; p++) {
      int idx = p * 256 + tid;
      int r = idx >> 7, cg = idx & 127;
      if (isA) dst4[(size_t)r * 256 + cg] = buf[p];
      *(unsigned*)&lq[0][r][cg * 4] =
          cvt4_fp8(buf[p][0] * scale, buf[p][1] * scale,
                   buf[p][2] * scale, buf[p][3] * scale);
    }
    // ---- issue all 8 loads of half 1 (in flight across barrier) ----
    #pragma unroll
    for (int p = 0; p < 8; p++) {
      int idx = p * 256 + tid;
      int r = idx >> 7, cg = idx & 127;
      buf[p] = src4[(size_t)r * 256 + 128 + cg];
    }
    asm volatile("s_waitcnt lgkmcnt(0)" ::: "memory");
    __builtin_amdgcn_s_barrier();

    // ---- gather half 0: frag-major stores (contiguous 16B/thread) ----
    #pragma unroll
    for (int cc = 0; cc < 2; cc++) {
      int c = cc * 256 + tid;          // 0..511
      int ktl = c >> 5, ci = c & 31;
      int r0 = (2 * ci) & 15, oct = ci >> 3;
      uint2 lo = *(const uint2*)&lq[0][r0][ktl * 32 + oct * 8];
      uint2 hi = *(const uint2*)&lq[0][r0 + 1][ktl * 32 + oct * 8];
      uint4 val = make_uint4(lo.x, lo.y, hi.x, hi.y);
      *(uint4*)(q8 + (size_t)ktl * 512 + ci * 16) = val;
    }
    // ---- consume half 1: copy write + HW fp8 -> LDS[1] ----
    #pragma unroll
    for (int p = 0; p < 8; p++) {
      int idx = p * 256 + tid;
      int r = idx >> 7, cg = idx & 127;
      if (isA) dst4[(size_t)r * 256 + 128 + cg] = buf[p];
      *(unsigned*)&lq[1][r][cg * 4] =
          cvt4_fp8(buf[p][0] * scale, buf[p][1] * scale,
                   buf[p][2] * scale, buf[p][3] * scale);
    }
    asm volatile("s_waitcnt lgkmcnt(0)" ::: "memory");
    __builtin_amdgcn_s_barrier();

    // ---- gather half 1 (kt 16..31) ----
    #pragma unroll
    for (int cc = 0; cc < 2; cc++) {
      int c = cc * 256 + tid;
      int ktl = c >> 5, ci = c & 31;
      int r0 = (2 * ci) & 15, oct = ci >> 3;
      uint2 lo = *(const uint2*)&lq[1][r0][ktl * 32 + oct * 8];
      uint2 hi = *(const uint2*)&lq[1][r0 + 1][ktl * 32 + oct * 8];
      uint4 val = make_uint4(lo.x, lo.y, hi.x, hi.y);
      *(uint4*)(q8 + (size_t)(16 + ktl) * 512 + ci * 16) = val;
    }
  } else if (bid < 2368) {               // ---- dec blocks ----
    int rel = bid - 2112;
    int lane = tid & 63, w = tid >> 6;
    int o = rel * 4 + w;
    const float4* wrow = (const float4*)(Ws + (size_t)o * H_DIM);
    float4 w0 = wrow[lane], w1 = wrow[64 + lane],
           w2 = wrow[128 + lane], w3 = wrow[192 + lane];
    const float4* st4 = (const float4*)st;
    float bias = bs[o];
    #pragma unroll 8
    for (int b = 0; b < B_DIM; b++) {
      const float4* s = st4 + (size_t)b * 256;
      float4 s0 = s[lane], s1 = s[64 + lane], s2 = s[128 + lane], s3 = s[192 + lane];
      float p = w0.x * s0.x + w0.y * s0.y + w0.z * s0.z + w0.w * s0.w
              + w1.x * s1.x + w1.y * s1.y + w1.z * s1.z + w1.w * s1.w
              + w2.x * s2.x + w2.y * s2.y + w2.z * s2.z + w2.w * s2.w
              + w3.x * s3.x + w3.y * s3.y + w3.z * s3.z + w3.w * s3.w;
      p += __shfl_xor(p, 1);  p += __shfl_xor(p, 2);
      p += __shfl_xor(p, 4);  p += __shfl_xor(p, 8);
      p += __shfl_xor(p, 16); p += __shfl_xor(p, 32);
      if (lane == 0) dec[(size_t)b * H_DIM + o] = p + bias;
    }
  } else {                                // ---- s_t tail rows ----
    const f32x4* s4 = (const f32x4*)st;
    for (int b = 0; b < B_DIM; b++) {
      f32x4* o4 = (f32x4*)out + 16384 + (size_t)b * 131328 + 131072;
      o4[tid] = s4[(size_t)b * 256 + tid];
    }
  }
}

// K3: fp8 score GEMM. 128x128 block, 2x2 waves of 64x64, BK=64,
// fragment-major LDS (linear stage, conflict-free ds_read_b64),
// raw-barrier + counted-vmcnt(4). acc = 64*et.
__global__ __launch_bounds__(256, 3) void score_gemm(
    const unsigned char* __restrict__ Aq,
    const unsigned char* __restrict__ Bq,
    const float* __restrict__ dec,
    const float* __restrict__ v,
    float* __restrict__ part)
{
  __shared__ __align__(16) unsigned char ldsA[2][8192];
  __shared__ __align__(16) unsigned char ldsB[2][8192];

  int orig = blockIdx.x;                       // 2048 blocks
  int swz = (orig & 7) * 256 + (orig >> 3);    // bijective XCD swizzle
  int bm = swz >> 3, bn = swz & 7;

  int tid = threadIdx.x;
  int lane = tid & 63, w = tid >> 6;
  int wm = w >> 1, wn = w & 1;                 // 2x2 waves, 64x64 each
  size_t m0 = (size_t)bm * 128;

  f32x4 acc[4][4];
  #pragma unroll
  for (int i = 0; i < 4; i++)
    #pragma unroll
    for (int j = 0; j < 4; j++) {
      f32x4 z; z[0] = 0.f; z[1] = 0.f; z[2] = 0.f; z[3] = 0.f;
      acc[i][j] = z;
    }

  int fA = tid >> 5, cif = tid & 31;
  const unsigned char* aSrc0 =
      Aq + ((size_t)(bm * 8 + (fA >> 1)) * 32 + (fA & 1)) * 512 + (size_t)cif * 16;
  const unsigned char* aSrc1 =
      Aq + ((size_t)(bm * 8 + (fA >> 1) + 4) * 32 + (fA & 1)) * 512 + (size_t)cif * 16;
  const unsigned char* bSrc0 =
      Bq + ((size_t)(bn * 8 + (fA >> 1)) * 32 + (fA & 1)) * 512 + (size_t)cif * 16;
  const unsigned char* bSrc1 =
      Bq + ((size_t)(bn * 8 + (fA >> 1) + 4) * 32 + (fA & 1)) * 512 + (size_t)cif * 16;

#define STAGE(buf, t) do { \
    size_t ko = (size_t)(t) * 1024; \
    gload_lds16(aSrc0 + ko, &ldsA[(buf)][tid * 16]); \
    gload_lds16(aSrc1 + ko, &ldsA[(buf)][tid * 16 + 4096]); \
    gload_lds16(bSrc0 + ko, &ldsB[(buf)][tid * 16]); \
    gload_lds16(bSrc1 + ko, &ldsB[(buf)][tid * 16 + 4096]); \
  } while (0)

  STAGE(0, 0);

  #pragma unroll 2
  for (int t = 0; t < 16; t++) {
    int cur = t & 1, nxt = cur ^ 1;
    if (t < 15) {
      STAGE(nxt, t + 1);
      asm volatile("s_waitcnt vmcnt(4)" ::: "memory");
    } else {
      asm volatile("s_waitcnt vmcnt(0)" ::: "memory");
    }
    __builtin_amdgcn_s_barrier();
    asm volatile("" ::: "memory");

    const unsigned char* Ac = &ldsA[cur][0];
    const unsigned char* Bc = &ldsB[cur][0];
    long av[4][2], bv[4][2];
    #pragma unroll
    for (int mf = 0; mf < 4; mf++)
      #pragma unroll
      for (int kk = 0; kk < 2; kk++)
        av[mf][kk] = *(const long*)(Ac + ((wm * 4 + mf) * 2 + kk) * 512 + lane * 8);
    #pragma unroll
    for (int nf = 0; nf < 4; nf++)
      #pragma unroll
      for (int kk = 0; kk < 2; kk++)
        bv[nf][kk] = *(const long*)(Bc + ((wn * 4 + nf) * 2 + kk) * 512 + lane * 8);

    __builtin_amdgcn_s_setprio(1);
    #pragma unroll
    for (int kk = 0; kk < 2; kk++)
      #pragma unroll
      for (int mf = 0; mf < 4; mf++)
        #pragma unroll
        for (int nf = 0; nf < 4; nf++)
          acc[mf][nf] = __builtin_amdgcn_mfma_f32_16x16x32_fp8_fp8(
              av[mf][kk], bv[nf][kk], acc[mf][nf], 0, 0, 0);
    __builtin_amdgcn_s_setprio(0);
    asm volatile("" ::: "memory");
    __builtin_amdgcn_s_barrier();
  }
#undef STAGE

  // epilogue: x = acc/64 + dec; tanh; dot v; 16-col shfl reduce; wn-pair via LDS
  int b = (int)(m0 >> 9);
  int lr = lane >> 4, lc = lane & 15;
  int n0 = bn * 128;
  float dv[4], vv[4];
  #pragma unroll
  for (int nf = 0; nf < 4; nf++) {
    int col = n0 + wn * 64 + nf * 16 + lc;
    dv[nf] = dec[(size_t)b * H_DIM + col];
    vv[nf] = v[col];
  }
  float* epi = (float*)&ldsA[0][0];  // [128 rows][2 wn] floats = 1KB
  #pragma unroll
  for (int mf = 0; mf < 4; mf++) {
    #pragma unroll
    for (int r = 0; r < 4; r++) {
      float s = 0.f;
      #pragma unroll
      for (int nf = 0; nf < 4; nf++) {
        float x = acc[mf][nf][r] * 0.015625f + dv[nf];
        x = fminf(fmaxf(x, -15.f), 15.f);
        float e = __expf(2.f * x);
        s += vv[nf] * (e - 1.f) * __builtin_amdgcn_rcpf(e + 1.f);
      }
      s += __shfl_xor(s, 1); s += __shfl_xor(s, 2);
      s += __shfl_xor(s, 4); s += __shfl_xor(s, 8);
      if (lc == 0) epi[(wm * 64 + mf * 16 + lr * 4 + r) * 2 + wn] = s;
    }
  }
  __syncthreads();
  if (tid < 128) {
    part[(m0 + tid) * 8 + bn] = epi[tid * 2] + epi[tid * 2 + 1];
  }
}

// K4: softmax over T per batch row (8 partials per row)
__global__ void softmax_kernel(const float* __restrict__ part, float* __restrict__ at) {
  int b = blockIdx.x, tid = threadIdx.x;
  __shared__ float sc[512];
  __shared__ float red[8];
  #pragma unroll
  for (int rep = 0; rep < 2; rep++) {
    int t = rep * 256 + tid;
    const float* p = part + ((size_t)b * 512 + t) * 8;
    sc[t] = p[0] + p[1] + p[2] + p[3] + p[4] + p[5] + p[6] + p[7];
  }
  __syncthreads();
  float m = fmaxf(sc[tid], sc[tid + 256]);
  for (int d = 1; d < 64; d <<= 1) m = fmaxf(m, __shfl_xor(m, d));
  if ((tid & 63) == 0) red[tid >> 6] = m;
  __syncthreads();
  m = fmaxf(fmaxf(red[0], red[1]), fmaxf(red[2], red[3]));
  float e0 = __expf(sc[tid] - m), e1 = __expf(sc[tid + 256] - m);
  float s = e0 + e1;
  for (int d = 1; d < 64; d <<= 1) s += __shfl_xor(s, d);
  if ((tid & 63) == 0) red[4 + (tid >> 6)] = s;
  __syncthreads();
  s = red[4] + red[5] + red[6] + red[7];
  float inv = 1.f / s;
  at[(size_t)b * 512 + tid] = e0 * inv;
  at[(size_t)b * 512 + tid + 256] = e1 * inv;
}

// K5: ct_d[b][h] = sum_t at[b][t] * prev[b][t][h] from fp8 frag-major A'
// (values are 4x -> scale 0.25). HW v_cvt_f32_fp8 decode (literal sels).
// One wave per (b, kt): in-wave reduction, no atomics.
__global__ void ctd_ws(const unsigned char* __restrict__ Aq,
                       const float* __restrict__ at, float* __restrict__ out) {
  int wid = blockIdx.x * 4 + (threadIdx.x >> 6);  // 2048 = 64 b x 32 kt
  int lane = threadIdx.x & 63;
  int b = wid >> 5, kt = wid & 31;
  int lc = lane & 15, lr = lane >> 4;
  float a8[8] = {0.f, 0.f, 0.f, 0.f, 0.f, 0.f, 0.f, 0.f};
  const unsigned char* base =
      Aq + ((size_t)b * 32 * 32 + kt) * 512 + (size_t)lane * 8;
  const float* atb = at + (size_t)b * 512;
  #pragma unroll 8
  for (int mt = 0; mt < 32; mt++) {
    float a = atb[mt * 16 + lc];
    uint2 uv = *(const uint2*)(base + (size_t)mt * 16384);
    a8[0] += a * __builtin_amdgcn_cvt_f32_fp8(uv.x, 0);
    a8[1] += a * __builtin_amdgcn_cvt_f32_fp8(uv.x, 1);
    a8[2] += a * __builtin_amdgcn_cvt_f32_fp8(uv.x, 2);
    a8[3] += a * __builtin_amdgcn_cvt_f32_fp8(uv.x, 3);
    a8[4] += a * __builtin_amdgcn_cvt_f32_fp8(uv.y, 0);
    a8[5] += a * __builtin_amdgcn_cvt_f32_fp8(uv.y, 1);
    a8[6] += a * __builtin_amdgcn_cvt_f32_fp8(uv.y, 2);
    a8[7] += a * __builtin_amdgcn_cvt_f32_fp8(uv.y, 3);
  }
  #pragma unroll
  for (int d = 1; d < 16; d <<= 1)
    #pragma unroll
    for (int j = 0; j < 8; j++) a8[j] += __shfl_xor(a8[j], d);
  if (lc == 0) {
    #pragma unroll
    for (int j = 0; j < 8; j++)
      out[(size_t)b * H_DIM + kt * 32 + lr * 8 + j] = a8[j] * 0.25f;
  }
}

extern "C" void kernel_launch(void* const* d_in, const int* in_sizes, int n_in,
                              void* d_out, int out_size, void* d_ws, size_t ws_size,
                              hipStream_t stream) {
  (void)in_sizes; (void)n_in; (void)out_size; (void)ws_size;
  const float* s_t    = (const float*)d_in[0];
  const float* prev_s = (const float*)d_in[1];
  const float* W_prev = (const float*)d_in[2];
  const float* W_s    = (const float*)d_in[3];
  const float* b_s    = (const float*)d_in[4];
  const float* v      = (const float*)d_in[5];
  float* out = (float*)d_out;
  char* ws = (char*)d_ws;

  unsigned char* Aq = (unsigned char*)(ws + AQ8_OFF);
  unsigned char* Wq = (unsigned char*)(ws + BQ8_OFF);
  float* dec  = (float*)(ws + DEC_OFF);
  float* part = (float*)(ws + PART_OFF);
  float* at   = (float*)(ws + AT_OFF);

  prep_ws<<<2369, 256, 0, stream>>>(prev_s, s_t, W_prev, W_s, b_s, out, Aq, Wq, dec);
  score_gemm<<<2048, 256, 0, stream>>>(Aq, Wq, dec, v, part);
  softmax_kernel<<<64, 256, 0, stream>>>(part, at);
  ctd_ws<<<512, 256, 0, stream>>>(Aq, at, out);
}

// Round 17
// 149.066 us; speedup vs baseline: 1.5061x; 1.0717x over previous
//
#include <hip/hip_runtime.h>
#include <hip/hip_bf16.h>

#define B_DIM 64
#define T_DIM 512
#define H_DIM 1024

typedef __attribute__((ext_vector_type(4))) float f32x4;

// ws layout (bytes)
#define AQ8_OFF  0UL              // A fp8 frag-major: 32768*1024 = 33554432
#define BQ8_OFF  33554432UL       // W fp8 frag-major: 1024*1024  =  1048576
#define DEC_OFF  34603008UL       // 64*1024*4  =  262144
#define PART_OFF 34865152UL       // 32768*8*4  = 1048576
#define AT_OFF   35913728UL       // 32768*4    =  131072
// total 36044800 bytes

// ---- fp8 e4m3fn: HW packed encode + HW decode ----
__device__ __forceinline__ unsigned cvt4_fp8(float a, float b, float c, float d) {
  unsigned r = 0;
  r = __builtin_amdgcn_cvt_pk_fp8_f32(a, b, r, false);   // bytes 0,1
  r = __builtin_amdgcn_cvt_pk_fp8_f32(c, d, r, true);    // bytes 2,3
  return r;
}

__device__ __forceinline__ void gload_lds16(const void* g, void* l) {
  __builtin_amdgcn_global_load_lds(
      (const __attribute__((address_space(1))) void*)g,
      (__attribute__((address_space(3))) void*)l, 16, 0, 0);
}

// Fragment-major fp8 layout (16x16x32 MFMA frags):
// frag(mt,kt) = 512B at ((mt*32)+kt)*512; lane l holds X[row=mt*16+(l&15)]
// [k = kt*32 + (l>>4)*8 + j], j=0..7.

// K1: mega-prep. Heterogeneous grid, SMALL WORK FIRST so it co-resides
// with (and hides under) the BW-bound A-stream:
//   bid 0..255    : dec blocks — dec_fea = W_s(s_t)+b_s
//   bid 256..2303 : A m-tiles — read prev, write fp32 concat copy + fp8 frags
//   bid 2304..2367: W n-tiles — fp8 frags
//   bid 2368      : s_t tail rows of concat
__global__ __launch_bounds__(256) void prep_ws(
    const float* __restrict__ prev,
    const float* __restrict__ st,
    const float* __restrict__ Wp,
    const float* __restrict__ Ws,
    const float* __restrict__ bs,
    float* __restrict__ out,
    unsigned char* __restrict__ Aq,
    unsigned char* __restrict__ Wq,
    float* __restrict__ dec) {
  __shared__ unsigned char lq[2][16][528];   // 528 = 512 + 16 pad
  int bid = blockIdx.x;
  int tid = threadIdx.x;

  if (bid < 256) {                       // ---- dec blocks (co-resident) ----
    int lane = tid & 63, w = tid >> 6;
    int o = bid * 4 + w;
    const float4* wrow = (const float4*)(Ws + (size_t)o * H_DIM);
    float4 w0 = wrow[lane], w1 = wrow[64 + lane],
           w2 = wrow[128 + lane], w3 = wrow[192 + lane];
    const float4* st4 = (const float4*)st;
    float bias = bs[o];
    #pragma unroll 8
    for (int b = 0; b < B_DIM; b++) {
      const float4* s = st4 + (size_t)b * 256;
      float4 s0 = s[lane], s1 = s[64 + lane], s2 = s[128 + lane], s3 = s[192 + lane];
      float p = w0.x * s0.x + w0.y * s0.y + w0.z * s0.z + w0.w * s0.w
              + w1.x * s1.x + w1.y * s1.y + w1.z * s1.z + w1.w * s1.w
              + w2.x * s2.x + w2.y * s2.y + w2.z * s2.z + w2.w * s2.w
              + w3.x * s3.x + w3.y * s3.y + w3.z * s3.z + w3.w * s3.w;
      p += __shfl_xor(p, 1);  p += __shfl_xor(p, 2);
      p += __shfl_xor(p, 4);  p += __shfl_xor(p, 8);
      p += __shfl_xor(p, 16); p += __shfl_xor(p, 32);
      if (lane == 0) dec[(size_t)b * H_DIM + o] = p + bias;
    }
  } else if (bid < 2368) {
    bool isA = bid < 2304;
    int mt = isA ? bid - 256 : bid - 2304;
    const f32x4* src4 = (const f32x4*)(isA ? prev : Wp) + (size_t)mt * 4096;
    f32x4* dst4 = nullptr;
    if (isA) {
      int b = mt >> 5, t0 = (mt & 31) * 16;
      dst4 = (f32x4*)out + 16384 + (size_t)b * 131328 + (size_t)t0 * 256;
    }
    unsigned char* q8 = (isA ? Aq : Wq) + (size_t)mt * 16384;  // 32 frags
    float scale = isA ? 4.f : 16.f;

    f32x4 buf[8];
    // ---- issue all 8 loads of half 0 ----
    #pragma unroll
    for (int p = 0; p < 8; p++) {
      int idx = p * 256 + tid;
      int r = idx >> 7, cg = idx & 127;
      buf[p] = src4[(size_t)r * 256 + cg];
    }
    // ---- consume half 0: copy write + HW fp8 -> LDS[0] ----
    #pragma unroll
    for (int p = 0; p < 8; p++) {
      int idx = p * 256 + tid;
      int r = idx >> 7, cg = idx & 127;
      if (isA) dst4[(size_t)r * 256 + cg] = buf[p];
      *(unsigned*)&lq[0][r][cg * 4] =
          cvt4_fp8(buf[p][0] * scale, buf[p][1] * scale,
                   buf[p][2] * scale, buf[p][3] * scale);
    }
    // ---- issue all 8 loads of half 1 (in flight across barrier) ----
    #pragma unroll
    for (int p = 0; p < 8; p++) {
      int idx = p * 256 + tid;
      int r = idx >> 7, cg = idx & 127;
      buf[p] = src4[(size_t)r * 256 + 128 + cg];
    }
    asm volatile("s_waitcnt lgkmcnt(0)" ::: "memory");
    __builtin_amdgcn_s_barrier();

    // ---- gather half 0: frag-major stores (contiguous 16B/thread) ----
    #pragma unroll
    for (int cc = 0; cc < 2; cc++) {
      int c = cc * 256 + tid;          // 0..511
      int ktl = c >> 5, ci = c & 31;
      int r0 = (2 * ci) & 15, oct = ci >> 3;
      uint2 lo = *(const uint2*)&lq[0][r0][ktl * 32 + oct * 8];
      uint2 hi = *(const uint2*)&lq[0][r0 + 1][ktl * 32 + oct * 8];
      uint4 val = make_uint4(lo.x, lo.y, hi.x, hi.y);
      *(uint4*)(q8 + (size_t)ktl * 512 + ci * 16) = val;
    }
    // ---- consume half 1: copy write + HW fp8 -> LDS[1] ----
    #pragma unroll
    for (int p = 0; p < 8; p++) {
      int idx = p * 256 + tid;
      int r = idx >> 7, cg = idx & 127;
      if (isA) dst4[(size_t)r * 256 + 128 + cg] = buf[p];
      *(unsigned*)&lq[1][r][cg * 4] =
          cvt4_fp8(buf[p][0] * scale, buf[p][1] * scale,
                   buf[p][2] * scale, buf[p][3] * scale);
    }
    asm volatile("s_waitcnt lgkmcnt(0)" ::: "memory");
    __builtin_amdgcn_s_barrier();

    // ---- gather half 1 (kt 16..31) ----
    #pragma unroll
    for (int cc = 0; cc < 2; cc++) {
      int c = cc * 256 + tid;
      int ktl = c >> 5, ci = c & 31;
      int r0 = (2 * ci) & 15, oct = ci >> 3;
      uint2 lo = *(const uint2*)&lq[1][r0][ktl * 32 + oct * 8];
      uint2 hi = *(const uint2*)&lq[1][r0 + 1][ktl * 32 + oct * 8];
      uint4 val = make_uint4(lo.x, lo.y, hi.x, hi.y);
      *(uint4*)(q8 + (size_t)(16 + ktl) * 512 + ci * 16) = val;
    }
  } else {                                // ---- s_t tail rows ----
    const f32x4* s4 = (const f32x4*)st;
    for (int b = 0; b < B_DIM; b++) {
      f32x4* o4 = (f32x4*)out + 16384 + (size_t)b * 131328 + 131072;
      o4[tid] = s4[(size_t)b * 256 + tid];
    }
  }
}

// K3: fp8 score GEMM. 128x128 block, 2x2 waves of 64x64, BK=64,
// fragment-major LDS (linear stage, conflict-free ds_read_b64),
// raw-barrier + counted-vmcnt(4). acc = 64*et.
__global__ __launch_bounds__(256, 3) void score_gemm(
    const unsigned char* __restrict__ Aq,
    const unsigned char* __restrict__ Bq,
    const float* __restrict__ dec,
    const float* __restrict__ v,
    float* __restrict__ part)
{
  __shared__ __align__(16) unsigned char ldsA[2][8192];
  __shared__ __align__(16) unsigned char ldsB[2][8192];

  int orig = blockIdx.x;                       // 2048 blocks
  int swz = (orig & 7) * 256 + (orig >> 3);    // bijective XCD swizzle
  int bm = swz >> 3, bn = swz & 7;

  int tid = threadIdx.x;
  int lane = tid & 63, w = tid >> 6;
  int wm = w >> 1, wn = w & 1;                 // 2x2 waves, 64x64 each
  size_t m0 = (size_t)bm * 128;

  f32x4 acc[4][4];
  #pragma unroll
  for (int i = 0; i < 4; i++)
    #pragma unroll
    for (int j = 0; j < 4; j++) {
      f32x4 z; z[0] = 0.f; z[1] = 0.f; z[2] = 0.f; z[3] = 0.f;
      acc[i][j] = z;
    }

  int fA = tid >> 5, cif = tid & 31;
  const unsigned char* aSrc0 =
      Aq + ((size_t)(bm * 8 + (fA >> 1)) * 32 + (fA & 1)) * 512 + (size_t)cif * 16;
  const unsigned char* aSrc1 =
      Aq + ((size_t)(bm * 8 + (fA >> 1) + 4) * 32 + (fA & 1)) * 512 + (size_t)cif * 16;
  const unsigned char* bSrc0 =
      Bq + ((size_t)(bn * 8 + (fA >> 1)) * 32 + (fA & 1)) * 512 + (size_t)cif * 16;
  const unsigned char* bSrc1 =
      Bq + ((size_t)(bn * 8 + (fA >> 1) + 4) * 32 + (fA & 1)) * 512 + (size_t)cif * 16;

#define STAGE(buf, t) do { \
    size_t ko = (size_t)(t) * 1024; \
    gload_lds16(aSrc0 + ko, &ldsA[(buf)][tid * 16]); \
    gload_lds16(aSrc1 + ko, &ldsA[(buf)][tid * 16 + 4096]); \
    gload_lds16(bSrc0 + ko, &ldsB[(buf)][tid * 16]); \
    gload_lds16(bSrc1 + ko, &ldsB[(buf)][tid * 16 + 4096]); \
  } while (0)

  STAGE(0, 0);

  #pragma unroll 2
  for (int t = 0; t < 16; t++) {
    int cur = t & 1, nxt = cur ^ 1;
    if (t < 15) {
      STAGE(nxt, t + 1);
      asm volatile("s_waitcnt vmcnt(4)" ::: "memory");
    } else {
      asm volatile("s_waitcnt vmcnt(0)" ::: "memory");
    }
    __builtin_amdgcn_s_barrier();
    asm volatile("" ::: "memory");

    const unsigned char* Ac = &ldsA[cur][0];
    const unsigned char* Bc = &ldsB[cur][0];
    long av[4][2], bv[4][2];
    #pragma unroll
    for (int mf = 0; mf < 4; mf++)
      #pragma unroll
      for (int kk = 0; kk < 2; kk++)
        av[mf][kk] = *(const long*)(Ac + ((wm * 4 + mf) * 2 + kk) * 512 + lane * 8);
    #pragma unroll
    for (int nf = 0; nf < 4; nf++)
      #pragma unroll
      for (int kk = 0; kk < 2; kk++)
        bv[nf][kk] = *(const long*)(Bc + ((wn * 4 + nf) * 2 + kk) * 512 + lane * 8);

    __builtin_amdgcn_s_setprio(1);
    #pragma unroll
    for (int kk = 0; kk < 2; kk++)
      #pragma unroll
      for (int mf = 0; mf < 4; mf++)
        #pragma unroll
        for (int nf = 0; nf < 4; nf++)
          acc[mf][nf] = __builtin_amdgcn_mfma_f32_16x16x32_fp8_fp8(
              av[mf][kk], bv[nf][kk], acc[mf][nf], 0, 0, 0);
    __builtin_amdgcn_s_setprio(0);
    asm volatile("" ::: "memory");
    __builtin_amdgcn_s_barrier();
  }
#undef STAGE

  // epilogue: x = acc/64 + dec; tanh; dot v; 16-col shfl reduce; wn-pair via LDS
  int b = (int)(m0 >> 9);
  int lr = lane >> 4, lc = lane & 15;
  int n0 = bn * 128;
  float dv[4], vv[4];
  #pragma unroll
  for (int nf = 0; nf < 4; nf++) {
    int col = n0 + wn * 64 + nf * 16 + lc;
    dv[nf] = dec[(size_t)b * H_DIM + col];
    vv[nf] = v[col];
  }
  float* epi = (float*)&ldsA[0][0];  // [128 rows][2 wn] floats = 1KB
  #pragma unroll
  for (int mf = 0; mf < 4; mf++) {
    #pragma unroll
    for (int r = 0; r < 4; r++) {
      float s = 0.f;
      #pragma unroll
      for (int nf = 0; nf < 4; nf++) {
        float x = acc[mf][nf][r] * 0.015625f + dv[nf];
        x = fminf(fmaxf(x, -15.f), 15.f);
        float e = __expf(2.f * x);
        s += vv[nf] * (e - 1.f) * __builtin_amdgcn_rcpf(e + 1.f);
      }
      s += __shfl_xor(s, 1); s += __shfl_xor(s, 2);
      s += __shfl_xor(s, 4); s += __shfl_xor(s, 8);
      if (lc == 0) epi[(wm * 64 + mf * 16 + lr * 4 + r) * 2 + wn] = s;
    }
  }
  __syncthreads();
  if (tid < 128) {
    part[(m0 + tid) * 8 + bn] = epi[tid * 2] + epi[tid * 2 + 1];
  }
}

// K4: softmax over T per batch row (8 partials per row)
__global__ void softmax_kernel(const float* __restrict__ part, float* __restrict__ at) {
  int b = blockIdx.x, tid = threadIdx.x;
  __shared__ float sc[512];
  __shared__ float red[8];
  #pragma unroll
  for (int rep = 0; rep < 2; rep++) {
    int t = rep * 256 + tid;
    const float* p = part + ((size_t)b * 512 + t) * 8;
    sc[t] = p[0] + p[1] + p[2] + p[3] + p[4] + p[5] + p[6] + p[7];
  }
  __syncthreads();
  float m = fmaxf(sc[tid], sc[tid + 256]);
  for (int d = 1; d < 64; d <<= 1) m = fmaxf(m, __shfl_xor(m, d));
  if ((tid & 63) == 0) red[tid >> 6] = m;
  __syncthreads();
  m = fmaxf(fmaxf(red[0], red[1]), fmaxf(red[2], red[3]));
  float e0 = __expf(sc[tid] - m), e1 = __expf(sc[tid + 256] - m);
  float s = e0 + e1;
  for (int d = 1; d < 64; d <<= 1) s += __shfl_xor(s, d);
  if ((tid & 63) == 0) red[4 + (tid >> 6)] = s;
  __syncthreads();
  s = red[4] + red[5] + red[6] + red[7];
  float inv = 1.f / s;
  at[(size_t)b * 512 + tid] = e0 * inv;
  at[(size_t)b * 512 + tid + 256] = e1 * inv;
}

// K5: ct_d[b][h] = sum_t at[b][t] * prev[b][t][h] from fp8 frag-major A'
// (values are 4x -> scale 0.25). HW v_cvt_f32_fp8 decode (literal sels).
// One wave per (b, kt): in-wave reduction, no atomics.
__global__ void ctd_ws(const unsigned char* __restrict__ Aq,
                       const float* __restrict__ at, float* __restrict__ out) {
  int wid = blockIdx.x * 4 + (threadIdx.x >> 6);  // 2048 = 64 b x 32 kt
  int lane = threadIdx.x & 63;
  int b = wid >> 5, kt = wid & 31;
  int lc = lane & 15, lr = lane >> 4;
  float a8[8] = {0.f, 0.f, 0.f, 0.f, 0.f, 0.f, 0.f, 0.f};
  const unsigned char* base =
      Aq + ((size_t)b * 32 * 32 + kt) * 512 + (size_t)lane * 8;
  const float* atb = at + (size_t)b * 512;
  #pragma unroll 8
  for (int mt = 0; mt < 32; mt++) {
    float a = atb[mt * 16 + lc];
    uint2 uv = *(const uint2*)(base + (size_t)mt * 16384);
    a8[0] += a * __builtin_amdgcn_cvt_f32_fp8(uv.x, 0);
    a8[1] += a * __builtin_amdgcn_cvt_f32_fp8(uv.x, 1);
    a8[2] += a * __builtin_amdgcn_cvt_f32_fp8(uv.x, 2);
    a8[3] += a * __builtin_amdgcn_cvt_f32_fp8(uv.x, 3);
    a8[4] += a * __builtin_amdgcn_cvt_f32_fp8(uv.y, 0);
    a8[5] += a * __builtin_amdgcn_cvt_f32_fp8(uv.y, 1);
    a8[6] += a * __builtin_amdgcn_cvt_f32_fp8(uv.y, 2);
    a8[7] += a * __builtin_amdgcn_cvt_f32_fp8(uv.y, 3);
  }
  #pragma unroll
  for (int d = 1; d < 16; d <<= 1)
    #pragma unroll
    for (int j = 0; j < 8; j++) a8[j] += __shfl_xor(a8[j], d);
  if (lc == 0) {
    #pragma unroll
    for (int j = 0; j < 8; j++)
      out[(size_t)b * H_DIM + kt * 32 + lr * 8 + j] = a8[j] * 0.25f;
  }
}

extern "C" void kernel_launch(void* const* d_in, const int* in_sizes, int n_in,
                              void* d_out, int out_size, void* d_ws, size_t ws_size,
                              hipStream_t stream) {
  (void)in_sizes; (void)n_in; (void)out_size; (void)ws_size;
  const float* s_t    = (const float*)d_in[0];
  const float* prev_s = (const float*)d_in[1];
  const float* W_prev = (const float*)d_in[2];
  const float* W_s    = (const float*)d_in[3];
  const float* b_s    = (const float*)d_in[4];
  const float* v      = (const float*)d_in[5];
  float* out = (float*)d_out;
  char* ws = (char*)d_ws;

  unsigned char* Aq = (unsigned char*)(ws + AQ8_OFF);
  unsigned char* Wq = (unsigned char*)(ws + BQ8_OFF);
  float* dec  = (float*)(ws + DEC_OFF);
  float* part = (float*)(ws + PART_OFF);
  float* at   = (float*)(ws + AT_OFF);

  prep_ws<<<2369, 256, 0, stream>>>(prev_s, s_t, W_prev, W_s, b_s, out, Aq, Wq, dec);
  score_gemm<<<2048, 256, 0, stream>>>(Aq, Wq, dec, v, part);
  softmax_kernel<<<64, 256, 0, stream>>>(part, at);
  ctd_ws<<<512, 256, 0, stream>>>(Aq, at, out);
}

// Round 18
// 147.993 us; speedup vs baseline: 1.5170x; 1.0073x over previous
//
#include <hip/hip_runtime.h>
#include <hip/hip_bf16.h>

#define B_DIM 64
#define T_DIM 512
#define H_DIM 1024

typedef __attribute__((ext_vector_type(4))) float f32x4;

// ws layout (bytes)
#define AQ8_OFF  0UL              // A fp8 frag-major: 32768*1024 = 33554432
#define BQ8_OFF  33554432UL       // W fp8 frag-major: 1024*1024  =  1048576
#define DEC_OFF  34603008UL       // 64*1024*4  =  262144
#define PART_OFF 34865152UL       // 32768*8*4  = 1048576
#define AT_OFF   35913728UL       // 32768*4    =  131072 (unused now)
// total 36044800 bytes

// ---- fp8 e4m3fn: HW packed encode + HW decode ----
__device__ __forceinline__ unsigned cvt4_fp8(float a, float b, float c, float d) {
  unsigned r = 0;
  r = __builtin_amdgcn_cvt_pk_fp8_f32(a, b, r, false);   // bytes 0,1
  r = __builtin_amdgcn_cvt_pk_fp8_f32(c, d, r, true);    // bytes 2,3
  return r;
}

__device__ __forceinline__ void gload_lds16(const void* g, void* l) {
  __builtin_amdgcn_global_load_lds(
      (const __attribute__((address_space(1))) void*)g,
      (__attribute__((address_space(3))) void*)l, 16, 0, 0);
}

// Fragment-major fp8 layout (16x16x32 MFMA frags):
// frag(mt,kt) = 512B at ((mt*32)+kt)*512; lane l holds X[row=mt*16+(l&15)]
// [k = kt*32 + (l>>4)*8 + j], j=0..7.

// K1: mega-prep v3. Heterogeneous grid with conv/copy INTERLEAVED so the
// pure-BW copy blocks fill the latency gaps of the barrier-bound conv blocks:
//   bid 0..255    : dec blocks
//   bid 256..4351 : rel=bid-256; even rel -> A-conv tile rel/2 (fp8 frags,
//                   NO copy); odd rel -> copy tile rel/2 (pure fp32 stream)
//   bid 4352..4415: W-conv n-tiles
//   bid 4416      : s_t tail rows
__global__ __launch_bounds__(256) void prep_ws(
    const float* __restrict__ prev,
    const float* __restrict__ st,
    const float* __restrict__ Wp,
    const float* __restrict__ Ws,
    const float* __restrict__ bs,
    float* __restrict__ out,
    unsigned char* __restrict__ Aq,
    unsigned char* __restrict__ Wq,
    float* __restrict__ dec) {
  __shared__ unsigned char lq[2][16][528];   // 528 = 512 + 16 pad
  int bid = blockIdx.x;
  int tid = threadIdx.x;

  if (bid < 256) {                       // ---- dec blocks (co-resident) ----
    int lane = tid & 63, w = tid >> 6;
    int o = bid * 4 + w;
    const float4* wrow = (const float4*)(Ws + (size_t)o * H_DIM);
    float4 w0 = wrow[lane], w1 = wrow[64 + lane],
           w2 = wrow[128 + lane], w3 = wrow[192 + lane];
    const float4* st4 = (const float4*)st;
    float bias = bs[o];
    #pragma unroll 8
    for (int b = 0; b < B_DIM; b++) {
      const float4* s = st4 + (size_t)b * 256;
      float4 s0 = s[lane], s1 = s[64 + lane], s2 = s[128 + lane], s3 = s[192 + lane];
      float p = w0.x * s0.x + w0.y * s0.y + w0.z * s0.z + w0.w * s0.w
              + w1.x * s1.x + w1.y * s1.y + w1.z * s1.z + w1.w * s1.w
              + w2.x * s2.x + w2.y * s2.y + w2.z * s2.z + w2.w * s2.w
              + w3.x * s3.x + w3.y * s3.y + w3.z * s3.z + w3.w * s3.w;
      p += __shfl_xor(p, 1);  p += __shfl_xor(p, 2);
      p += __shfl_xor(p, 4);  p += __shfl_xor(p, 8);
      p += __shfl_xor(p, 16); p += __shfl_xor(p, 32);
      if (lane == 0) dec[(size_t)b * H_DIM + o] = p + bias;
    }
  } else if (bid < 4352 && ((bid - 256) & 1)) {
    // ---- copy block: pure fp32 stream, tile mt = (bid-256)/2 ----
    int mt = (bid - 256) >> 1;
    const f32x4* src4 = (const f32x4*)prev + (size_t)mt * 4096;
    int b = mt >> 5, t0 = (mt & 31) * 16;
    f32x4* dst4 = (f32x4*)out + 16384 + (size_t)b * 131328 + (size_t)t0 * 256;
    f32x4 cb[8];
    #pragma unroll
    for (int p = 0; p < 8; p++) cb[p] = src4[p * 256 + tid];
    #pragma unroll
    for (int p = 0; p < 8; p++) dst4[p * 256 + tid] = cb[p];
    #pragma unroll
    for (int p = 0; p < 8; p++) cb[p] = src4[2048 + p * 256 + tid];
    #pragma unroll
    for (int p = 0; p < 8; p++) dst4[2048 + p * 256 + tid] = cb[p];
  } else if (bid < 4416) {
    // ---- conv block (A even-interleaved, or W at the end) ----
    bool isA = bid < 4352;
    int mt = isA ? ((bid - 256) >> 1) : (bid - 4352);
    const f32x4* src4 = (const f32x4*)(isA ? prev : Wp) + (size_t)mt * 4096;
    unsigned char* q8 = (isA ? Aq : Wq) + (size_t)mt * 16384;  // 32 frags
    float scale = isA ? 4.f : 16.f;

    f32x4 buf[8];
    // ---- issue all 8 loads of half 0 ----
    #pragma unroll
    for (int p = 0; p < 8; p++) {
      int idx = p * 256 + tid;
      int r = idx >> 7, cg = idx & 127;
      buf[p] = src4[(size_t)r * 256 + cg];
    }
    // ---- consume half 0: HW fp8 -> LDS[0] ----
    #pragma unroll
    for (int p = 0; p < 8; p++) {
      int idx = p * 256 + tid;
      int r = idx >> 7, cg = idx & 127;
      *(unsigned*)&lq[0][r][cg * 4] =
          cvt4_fp8(buf[p][0] * scale, buf[p][1] * scale,
                   buf[p][2] * scale, buf[p][3] * scale);
    }
    // ---- issue all 8 loads of half 1 (in flight across barrier) ----
    #pragma unroll
    for (int p = 0; p < 8; p++) {
      int idx = p * 256 + tid;
      int r = idx >> 7, cg = idx & 127;
      buf[p] = src4[(size_t)r * 256 + 128 + cg];
    }
    asm volatile("s_waitcnt lgkmcnt(0)" ::: "memory");
    __builtin_amdgcn_s_barrier();

    // ---- gather half 0: frag-major stores (contiguous 16B/thread) ----
    #pragma unroll
    for (int cc = 0; cc < 2; cc++) {
      int c = cc * 256 + tid;          // 0..511
      int ktl = c >> 5, ci = c & 31;
      int r0 = (2 * ci) & 15, oct = ci >> 3;
      uint2 lo = *(const uint2*)&lq[0][r0][ktl * 32 + oct * 8];
      uint2 hi = *(const uint2*)&lq[0][r0 + 1][ktl * 32 + oct * 8];
      uint4 val = make_uint4(lo.x, lo.y, hi.x, hi.y);
      *(uint4*)(q8 + (size_t)ktl * 512 + ci * 16) = val;
    }
    // ---- consume half 1: HW fp8 -> LDS[1] ----
    #pragma unroll
    for (int p = 0; p < 8; p++) {
      int idx = p * 256 + tid;
      int r = idx >> 7, cg = idx & 127;
      *(unsigned*)&lq[1][r][cg * 4] =
          cvt4_fp8(buf[p][0] * scale, buf[p][1] * scale,
                   buf[p][2] * scale, buf[p][3] * scale);
    }
    asm volatile("s_waitcnt lgkmcnt(0)" ::: "memory");
    __builtin_amdgcn_s_barrier();

    // ---- gather half 1 (kt 16..31) ----
    #pragma unroll
    for (int cc = 0; cc < 2; cc++) {
      int c = cc * 256 + tid;
      int ktl = c >> 5, ci = c & 31;
      int r0 = (2 * ci) & 15, oct = ci >> 3;
      uint2 lo = *(const uint2*)&lq[1][r0][ktl * 32 + oct * 8];
      uint2 hi = *(const uint2*)&lq[1][r0 + 1][ktl * 32 + oct * 8];
      uint4 val = make_uint4(lo.x, lo.y, hi.x, hi.y);
      *(uint4*)(q8 + (size_t)(16 + ktl) * 512 + ci * 16) = val;
    }
  } else {                                // ---- s_t tail rows ----
    const f32x4* s4 = (const f32x4*)st;
    for (int b = 0; b < B_DIM; b++) {
      f32x4* o4 = (f32x4*)out + 16384 + (size_t)b * 131328 + 131072;
      o4[tid] = s4[(size_t)b * 256 + tid];
    }
  }
}

// K3: fp8 score GEMM. 128x128 block, 2x2 waves of 64x64, BK=64,
// fragment-major LDS (linear stage, conflict-free ds_read_b64),
// raw-barrier + counted-vmcnt(4). acc = 64*et.
__global__ __launch_bounds__(256, 3) void score_gemm(
    const unsigned char* __restrict__ Aq,
    const unsigned char* __restrict__ Bq,
    const float* __restrict__ dec,
    const float* __restrict__ v,
    float* __restrict__ part)
{
  __shared__ __align__(16) unsigned char ldsA[2][8192];
  __shared__ __align__(16) unsigned char ldsB[2][8192];

  int orig = blockIdx.x;                       // 2048 blocks
  int swz = (orig & 7) * 256 + (orig >> 3);    // bijective XCD swizzle
  int bm = swz >> 3, bn = swz & 7;

  int tid = threadIdx.x;
  int lane = tid & 63, w = tid >> 6;
  int wm = w >> 1, wn = w & 1;                 // 2x2 waves, 64x64 each
  size_t m0 = (size_t)bm * 128;

  f32x4 acc[4][4];
  #pragma unroll
  for (int i = 0; i < 4; i++)
    #pragma unroll
    for (int j = 0; j < 4; j++) {
      f32x4 z; z[0] = 0.f; z[1] = 0.f; z[2] = 0.f; z[3] = 0.f;
      acc[i][j] = z;
    }

  int fA = tid >> 5, cif = tid & 31;
  const unsigned char* aSrc0 =
      Aq + ((size_t)(bm * 8 + (fA >> 1)) * 32 + (fA & 1)) * 512 + (size_t)cif * 16;
  const unsigned char* aSrc1 =
      Aq + ((size_t)(bm * 8 + (fA >> 1) + 4) * 32 + (fA & 1)) * 512 + (size_t)cif * 16;
  const unsigned char* bSrc0 =
      Bq + ((size_t)(bn * 8 + (fA >> 1)) * 32 + (fA & 1)) * 512 + (size_t)cif * 16;
  const unsigned char* bSrc1 =
      Bq + ((size_t)(bn * 8 + (fA >> 1) + 4) * 32 + (fA & 1)) * 512 + (size_t)cif * 16;

#define STAGE(buf, t) do { \
    size_t ko = (size_t)(t) * 1024; \
    gload_lds16(aSrc0 + ko, &ldsA[(buf)][tid * 16]); \
    gload_lds16(aSrc1 + ko, &ldsA[(buf)][tid * 16 + 4096]); \
    gload_lds16(bSrc0 + ko, &ldsB[(buf)][tid * 16]); \
    gload_lds16(bSrc1 + ko, &ldsB[(buf)][tid * 16 + 4096]); \
  } while (0)

  STAGE(0, 0);

  #pragma unroll 2
  for (int t = 0; t < 16; t++) {
    int cur = t & 1, nxt = cur ^ 1;
    if (t < 15) {
      STAGE(nxt, t + 1);
      asm volatile("s_waitcnt vmcnt(4)" ::: "memory");
    } else {
      asm volatile("s_waitcnt vmcnt(0)" ::: "memory");
    }
    __builtin_amdgcn_s_barrier();
    asm volatile("" ::: "memory");

    const unsigned char* Ac = &ldsA[cur][0];
    const unsigned char* Bc = &ldsB[cur][0];
    long av[4][2], bv[4][2];
    #pragma unroll
    for (int mf = 0; mf < 4; mf++)
      #pragma unroll
      for (int kk = 0; kk < 2; kk++)
        av[mf][kk] = *(const long*)(Ac + ((wm * 4 + mf) * 2 + kk) * 512 + lane * 8);
    #pragma unroll
    for (int nf = 0; nf < 4; nf++)
      #pragma unroll
      for (int kk = 0; kk < 2; kk++)
        bv[nf][kk] = *(const long*)(Bc + ((wn * 4 + nf) * 2 + kk) * 512 + lane * 8);

    __builtin_amdgcn_s_setprio(1);
    #pragma unroll
    for (int kk = 0; kk < 2; kk++)
      #pragma unroll
      for (int mf = 0; mf < 4; mf++)
        #pragma unroll
        for (int nf = 0; nf < 4; nf++)
          acc[mf][nf] = __builtin_amdgcn_mfma_f32_16x16x32_fp8_fp8(
              av[mf][kk], bv[nf][kk], acc[mf][nf], 0, 0, 0);
    __builtin_amdgcn_s_setprio(0);
    asm volatile("" ::: "memory");
    __builtin_amdgcn_s_barrier();
  }
#undef STAGE

  // epilogue: x = acc/64 + dec; tanh; dot v; 16-col shfl reduce; wn-pair via LDS
  int b = (int)(m0 >> 9);
  int lr = lane >> 4, lc = lane & 15;
  int n0 = bn * 128;
  float dv[4], vv[4];
  #pragma unroll
  for (int nf = 0; nf < 4; nf++) {
    int col = n0 + wn * 64 + nf * 16 + lc;
    dv[nf] = dec[(size_t)b * H_DIM + col];
    vv[nf] = v[col];
  }
  float* epi = (float*)&ldsA[0][0];  // [128 rows][2 wn] floats = 1KB
  #pragma unroll
  for (int mf = 0; mf < 4; mf++) {
    #pragma unroll
    for (int r = 0; r < 4; r++) {
      float s = 0.f;
      #pragma unroll
      for (int nf = 0; nf < 4; nf++) {
        float x = acc[mf][nf][r] * 0.015625f + dv[nf];
        x = fminf(fmaxf(x, -15.f), 15.f);
        float e = __expf(2.f * x);
        s += vv[nf] * (e - 1.f) * __builtin_amdgcn_rcpf(e + 1.f);
      }
      s += __shfl_xor(s, 1); s += __shfl_xor(s, 2);
      s += __shfl_xor(s, 4); s += __shfl_xor(s, 8);
      if (lc == 0) epi[(wm * 64 + mf * 16 + lr * 4 + r) * 2 + wn] = s;
    }
  }
  __syncthreads();
  if (tid < 128) {
    part[(m0 + tid) * 8 + bn] = epi[tid * 2] + epi[tid * 2 + 1];
  }
}

// K5: fused softmax + ct_d. 512 blocks = 64 b x 8 kt-groups; each block
// redundantly computes its batch's 512-row softmax from part into LDS
// (replaces the separate softmax kernel), then does the fp8 weighted
// reduction with HW v_cvt_f32_fp8 decode. No atomics.
__global__ __launch_bounds__(256) void ctd_ws(
    const unsigned char* __restrict__ Aq,
    const float* __restrict__ part,
    float* __restrict__ out) {
  __shared__ float sc[512];
  __shared__ float red[8];
  __shared__ float at_l[512];
  int blk = blockIdx.x;
  int tid = threadIdx.x;
  int b = blk >> 3;

  // ---- softmax over T for batch b (identical math to old kernel) ----
  #pragma unroll
  for (int rep = 0; rep < 2; rep++) {
    int t = rep * 256 + tid;
    const float* p = part + ((size_t)b * 512 + t) * 8;
    sc[t] = p[0] + p[1] + p[2] + p[3] + p[4] + p[5] + p[6] + p[7];
  }
  __syncthreads();
  float m = fmaxf(sc[tid], sc[tid + 256]);
  for (int d = 1; d < 64; d <<= 1) m = fmaxf(m, __shfl_xor(m, d));
  if ((tid & 63) == 0) red[tid >> 6] = m;
  __syncthreads();
  m = fmaxf(fmaxf(red[0], red[1]), fmaxf(red[2], red[3]));
  float e0 = __expf(sc[tid] - m), e1 = __expf(sc[tid + 256] - m);
  float s = e0 + e1;
  for (int d = 1; d < 64; d <<= 1) s += __shfl_xor(s, d);
  if ((tid & 63) == 0) red[4 + (tid >> 6)] = s;
  __syncthreads();
  s = red[4] + red[5] + red[6] + red[7];
  float inv = 1.f / s;
  at_l[tid] = e0 * inv;
  at_l[tid + 256] = e1 * inv;
  __syncthreads();

  // ---- weighted reduction: ct_d[b][kt*32..+32) ----
  int lane = tid & 63, w = tid >> 6;
  int kt = (blk & 7) * 4 + w;
  int lc = lane & 15, lr = lane >> 4;
  float a8[8] = {0.f, 0.f, 0.f, 0.f, 0.f, 0.f, 0.f, 0.f};
  const unsigned char* base =
      Aq + ((size_t)b * 1024 + kt) * 512 + (size_t)lane * 8;
  #pragma unroll 8
  for (int mt = 0; mt < 32; mt++) {
    float a = at_l[mt * 16 + lc];
    uint2 uv = *(const uint2*)(base + (size_t)mt * 16384);
    a8[0] += a * __builtin_amdgcn_cvt_f32_fp8(uv.x, 0);
    a8[1] += a * __builtin_amdgcn_cvt_f32_fp8(uv.x, 1);
    a8[2] += a * __builtin_amdgcn_cvt_f32_fp8(uv.x, 2);
    a8[3] += a * __builtin_amdgcn_cvt_f32_fp8(uv.x, 3);
    a8[4] += a * __builtin_amdgcn_cvt_f32_fp8(uv.y, 0);
    a8[5] += a * __builtin_amdgcn_cvt_f32_fp8(uv.y, 1);
    a8[6] += a * __builtin_amdgcn_cvt_f32_fp8(uv.y, 2);
    a8[7] += a * __builtin_amdgcn_cvt_f32_fp8(uv.y, 3);
  }
  #pragma unroll
  for (int d = 1; d < 16; d <<= 1)
    #pragma unroll
    for (int j = 0; j < 8; j++) a8[j] += __shfl_xor(a8[j], d);
  if (lc == 0) {
    #pragma unroll
    for (int j = 0; j < 8; j++)
      out[(size_t)b * H_DIM + kt * 32 + lr * 8 + j] = a8[j] * 0.25f;
  }
}

extern "C" void kernel_launch(void* const* d_in, const int* in_sizes, int n_in,
                              void* d_out, int out_size, void* d_ws, size_t ws_size,
                              hipStream_t stream) {
  (void)in_sizes; (void)n_in; (void)out_size; (void)ws_size;
  const float* s_t    = (const float*)d_in[0];
  const float* prev_s = (const float*)d_in[1];
  const float* W_prev = (const float*)d_in[2];
  const float* W_s    = (const float*)d_in[3];
  const float* b_s    = (const float*)d_in[4];
  const float* v      = (const float*)d_in[5];
  float* out = (float*)d_out;
  char* ws = (char*)d_ws;

  unsigned char* Aq = (unsigned char*)(ws + AQ8_OFF);
  unsigned char* Wq = (unsigned char*)(ws + BQ8_OFF);
  float* dec  = (float*)(ws + DEC_OFF);
  float* part = (float*)(ws + PART_OFF);

  prep_ws<<<4417, 256, 0, stream>>>(prev_s, s_t, W_prev, W_s, b_s, out, Aq, Wq, dec);
  score_gemm<<<2048, 256, 0, stream>>>(Aq, Wq, dec, v, part);
  ctd_ws<<<512, 256, 0, stream>>>(Aq, part, out);
}

// Round 19
// 134.643 us; speedup vs baseline: 1.6674x; 1.0991x over previous
//
#include <hip/hip_runtime.h>
#include <hip/hip_bf16.h>

#define B_DIM 64
#define T_DIM 512
#define H_DIM 1024

typedef __attribute__((ext_vector_type(4))) float f32x4;

// ws layout (bytes)
#define AQ8_OFF  0UL              // A fp8 frag-major: 32768*1024 = 33554432
#define BQ8_OFF  33554432UL       // W fp8 frag-major: 1024*1024  =  1048576
#define DEC_OFF  34603008UL       // 64*1024*4  =  262144
#define PART_OFF 34865152UL       // 32768*8*4  = 1048576
// total 35913728 bytes

// ---- fp8 e4m3fn: HW packed encode + HW decode ----
__device__ __forceinline__ unsigned cvt4_fp8(float a, float b, float c, float d) {
  unsigned r = 0;
  r = __builtin_amdgcn_cvt_pk_fp8_f32(a, b, r, false);   // bytes 0,1
  r = __builtin_amdgcn_cvt_pk_fp8_f32(c, d, r, true);    // bytes 2,3
  return r;
}

__device__ __forceinline__ void gload_lds16(const void* g, void* l) {
  __builtin_amdgcn_global_load_lds(
      (const __attribute__((address_space(1))) void*)g,
      (__attribute__((address_space(3))) void*)l, 16, 0, 0);
}

// Fragment-major fp8 layout (16x16x32 MFMA frags):
// frag(mt,kt) = 512B at ((mt*32)+kt)*512; lane l holds X[row=mt*16+(l&15)]
// [k = kt*32 + (l>>4)*8 + j], j=0..7.

// K1: mega-prep v4 — BARRIER-FREE transpose. Each wave owns a k-quarter
// (16 rows x 256 cols) of its tile; its LDS slice is wave-private, so only
// s_waitcnt lgkmcnt(0) is needed (same-wave ordering). Copy stream fused
// on the single prev read.
//   bid 0..255    : dec blocks
//   bid 256..2303 : A m-tiles (read prev once: fp32 copy + fp8 frags)
//   bid 2304..2367: W n-tiles
//   bid 2368      : s_t tail rows
__global__ __launch_bounds__(256) void prep_ws(
    const float* __restrict__ prev,
    const float* __restrict__ st,
    const float* __restrict__ Wp,
    const float* __restrict__ Ws,
    const float* __restrict__ bs,
    float* __restrict__ out,
    unsigned char* __restrict__ Aq,
    unsigned char* __restrict__ Wq,
    float* __restrict__ dec) {
  __shared__ unsigned char lq[4][16][264];   // per-wave slices, 264 = 256+8 pad
  int bid = blockIdx.x;
  int tid = threadIdx.x;
  int lane = tid & 63, w = tid >> 6;

  if (bid < 256) {                       // ---- dec blocks (co-resident) ----
    int o = bid * 4 + w;
    const float4* wrow = (const float4*)(Ws + (size_t)o * H_DIM);
    float4 w0 = wrow[lane], w1 = wrow[64 + lane],
           w2 = wrow[128 + lane], w3 = wrow[192 + lane];
    const float4* st4 = (const float4*)st;
    float bias = bs[o];
    #pragma unroll 8
    for (int b = 0; b < B_DIM; b++) {
      const float4* s = st4 + (size_t)b * 256;
      float4 s0 = s[lane], s1 = s[64 + lane], s2 = s[128 + lane], s3 = s[192 + lane];
      float p = w0.x * s0.x + w0.y * s0.y + w0.z * s0.z + w0.w * s0.w
              + w1.x * s1.x + w1.y * s1.y + w1.z * s1.z + w1.w * s1.w
              + w2.x * s2.x + w2.y * s2.y + w2.z * s2.z + w2.w * s2.w
              + w3.x * s3.x + w3.y * s3.y + w3.z * s3.z + w3.w * s3.w;
      p += __shfl_xor(p, 1);  p += __shfl_xor(p, 2);
      p += __shfl_xor(p, 4);  p += __shfl_xor(p, 8);
      p += __shfl_xor(p, 16); p += __shfl_xor(p, 32);
      if (lane == 0) dec[(size_t)b * H_DIM + o] = p + bias;
    }
  } else if (bid < 2368) {
    bool isA = bid < 2304;
    int mt = isA ? bid - 256 : bid - 2304;
    const f32x4* src4 = (const f32x4*)(isA ? prev : Wp) + (size_t)mt * 4096;
    f32x4* dst4 = nullptr;
    if (isA) {
      int b = mt >> 5, t0 = (mt & 31) * 16;
      dst4 = (f32x4*)out + 16384 + (size_t)b * 131328 + (size_t)t0 * 256;
    }
    unsigned char* q8 = (isA ? Aq : Wq) + (size_t)mt * 16384;  // 32 frags
    float scale = isA ? 4.f : 16.f;

    // wave w owns k-quarter w: rows 0..15, float4 cols w*64 .. w*64+63
    f32x4 buf[16];
    #pragma unroll
    for (int r = 0; r < 16; r++)
      buf[r] = src4[(size_t)r * 256 + w * 64 + lane];
    #pragma unroll
    for (int r = 0; r < 16; r++) {
      if (isA) dst4[(size_t)r * 256 + w * 64 + lane] = buf[r];
      *(unsigned*)&lq[w][r][lane * 4] =
          cvt4_fp8(buf[r][0] * scale, buf[r][1] * scale,
                   buf[r][2] * scale, buf[r][3] * scale);
    }
    asm volatile("s_waitcnt lgkmcnt(0)" ::: "memory");  // wave-private LDS ready

    // gather: wave's 8 frags (global kt = w*8+f); 8B/lane, 512B/frag store
    #pragma unroll
    for (int f = 0; f < 8; f++) {
      uint2 val = *(const uint2*)&lq[w][lane & 15][f * 32 + (lane >> 4) * 8];
      *(uint2*)(q8 + (size_t)(w * 8 + f) * 512 + lane * 8) = val;
    }
  } else {                                // ---- s_t tail rows ----
    const f32x4* s4 = (const f32x4*)st;
    for (int b = 0; b < B_DIM; b++) {
      f32x4* o4 = (f32x4*)out + 16384 + (size_t)b * 131328 + 131072;
      o4[tid] = s4[(size_t)b * 256 + tid];
    }
  }
}

// K3: fp8 score GEMM. 128x128 block, 2x2 waves of 64x64, BK=64,
// fragment-major LDS (linear stage, conflict-free ds_read_b64),
// raw-barrier + counted-vmcnt(4). acc = 64*et.
__global__ __launch_bounds__(256, 3) void score_gemm(
    const unsigned char* __restrict__ Aq,
    const unsigned char* __restrict__ Bq,
    const float* __restrict__ dec,
    const float* __restrict__ v,
    float* __restrict__ part)
{
  __shared__ __align__(16) unsigned char ldsA[2][8192];
  __shared__ __align__(16) unsigned char ldsB[2][8192];

  int orig = blockIdx.x;                       // 2048 blocks
  int swz = (orig & 7) * 256 + (orig >> 3);    // bijective XCD swizzle
  int bm = swz >> 3, bn = swz & 7;

  int tid = threadIdx.x;
  int lane = tid & 63, w = tid >> 6;
  int wm = w >> 1, wn = w & 1;                 // 2x2 waves, 64x64 each
  size_t m0 = (size_t)bm * 128;

  f32x4 acc[4][4];
  #pragma unroll
  for (int i = 0; i < 4; i++)
    #pragma unroll
    for (int j = 0; j < 4; j++) {
      f32x4 z; z[0] = 0.f; z[1] = 0.f; z[2] = 0.f; z[3] = 0.f;
      acc[i][j] = z;
    }

  int fA = tid >> 5, cif = tid & 31;
  const unsigned char* aSrc0 =
      Aq + ((size_t)(bm * 8 + (fA >> 1)) * 32 + (fA & 1)) * 512 + (size_t)cif * 16;
  const unsigned char* aSrc1 =
      Aq + ((size_t)(bm * 8 + (fA >> 1) + 4) * 32 + (fA & 1)) * 512 + (size_t)cif * 16;
  const unsigned char* bSrc0 =
      Bq + ((size_t)(bn * 8 + (fA >> 1)) * 32 + (fA & 1)) * 512 + (size_t)cif * 16;
  const unsigned char* bSrc1 =
      Bq + ((size_t)(bn * 8 + (fA >> 1) + 4) * 32 + (fA & 1)) * 512 + (size_t)cif * 16;

#define STAGE(buf, t) do { \
    size_t ko = (size_t)(t) * 1024; \
    gload_lds16(aSrc0 + ko, &ldsA[(buf)][tid * 16]); \
    gload_lds16(aSrc1 + ko, &ldsA[(buf)][tid * 16 + 4096]); \
    gload_lds16(bSrc0 + ko, &ldsB[(buf)][tid * 16]); \
    gload_lds16(bSrc1 + ko, &ldsB[(buf)][tid * 16 + 4096]); \
  } while (0)

  STAGE(0, 0);

  #pragma unroll 2
  for (int t = 0; t < 16; t++) {
    int cur = t & 1, nxt = cur ^ 1;
    if (t < 15) {
      STAGE(nxt, t + 1);
      asm volatile("s_waitcnt vmcnt(4)" ::: "memory");
    } else {
      asm volatile("s_waitcnt vmcnt(0)" ::: "memory");
    }
    __builtin_amdgcn_s_barrier();
    asm volatile("" ::: "memory");

    const unsigned char* Ac = &ldsA[cur][0];
    const unsigned char* Bc = &ldsB[cur][0];
    long av[4][2], bv[4][2];
    #pragma unroll
    for (int mf = 0; mf < 4; mf++)
      #pragma unroll
      for (int kk = 0; kk < 2; kk++)
        av[mf][kk] = *(const long*)(Ac + ((wm * 4 + mf) * 2 + kk) * 512 + lane * 8);
    #pragma unroll
    for (int nf = 0; nf < 4; nf++)
      #pragma unroll
      for (int kk = 0; kk < 2; kk++)
        bv[nf][kk] = *(const long*)(Bc + ((wn * 4 + nf) * 2 + kk) * 512 + lane * 8);

    __builtin_amdgcn_s_setprio(1);
    #pragma unroll
    for (int kk = 0; kk < 2; kk++)
      #pragma unroll
      for (int mf = 0; mf < 4; mf++)
        #pragma unroll
        for (int nf = 0; nf < 4; nf++)
          acc[mf][nf] = __builtin_amdgcn_mfma_f32_16x16x32_fp8_fp8(
              av[mf][kk], bv[nf][kk], acc[mf][nf], 0, 0, 0);
    __builtin_amdgcn_s_setprio(0);
    asm volatile("" ::: "memory");
    __builtin_amdgcn_s_barrier();
  }
#undef STAGE

  // epilogue: x = acc/64 + dec; tanh; dot v; 16-col shfl reduce; wn-pair via LDS
  int b = (int)(m0 >> 9);
  int lr = lane >> 4, lc = lane & 15;
  int n0 = bn * 128;
  float dv[4], vv[4];
  #pragma unroll
  for (int nf = 0; nf < 4; nf++) {
    int col = n0 + wn * 64 + nf * 16 + lc;
    dv[nf] = dec[(size_t)b * H_DIM + col];
    vv[nf] = v[col];
  }
  float* epi = (float*)&ldsA[0][0];  // [128 rows][2 wn] floats = 1KB
  #pragma unroll
  for (int mf = 0; mf < 4; mf++) {
    #pragma unroll
    for (int r = 0; r < 4; r++) {
      float s = 0.f;
      #pragma unroll
      for (int nf = 0; nf < 4; nf++) {
        float x = acc[mf][nf][r] * 0.015625f + dv[nf];
        x = fminf(fmaxf(x, -15.f), 15.f);
        float e = __expf(2.f * x);
        s += vv[nf] * (e - 1.f) * __builtin_amdgcn_rcpf(e + 1.f);
      }
      s += __shfl_xor(s, 1); s += __shfl_xor(s, 2);
      s += __shfl_xor(s, 4); s += __shfl_xor(s, 8);
      if (lc == 0) epi[(wm * 64 + mf * 16 + lr * 4 + r) * 2 + wn] = s;
    }
  }
  __syncthreads();
  if (tid < 128) {
    part[(m0 + tid) * 8 + bn] = epi[tid * 2] + epi[tid * 2 + 1];
  }
}

// K5: fused softmax + ct_d. 512 blocks = 64 b x 8 kt-groups; each block
// redundantly computes its batch's 512-row softmax from part into LDS,
// then does the fp8 weighted reduction with HW v_cvt_f32_fp8 decode.
__global__ __launch_bounds__(256) void ctd_ws(
    const unsigned char* __restrict__ Aq,
    const float* __restrict__ part,
    float* __restrict__ out) {
  __shared__ float sc[512];
  __shared__ float red[8];
  __shared__ float at_l[512];
  int blk = blockIdx.x;
  int tid = threadIdx.x;
  int b = blk >> 3;

  // ---- softmax over T for batch b ----
  #pragma unroll
  for (int rep = 0; rep < 2; rep++) {
    int t = rep * 256 + tid;
    const float* p = part + ((size_t)b * 512 + t) * 8;
    sc[t] = p[0] + p[1] + p[2] + p[3] + p[4] + p[5] + p[6] + p[7];
  }
  __syncthreads();
  float m = fmaxf(sc[tid], sc[tid + 256]);
  for (int d = 1; d < 64; d <<= 1) m = fmaxf(m, __shfl_xor(m, d));
  if ((tid & 63) == 0) red[tid >> 6] = m;
  __syncthreads();
  m = fmaxf(fmaxf(red[0], red[1]), fmaxf(red[2], red[3]));
  float e0 = __expf(sc[tid] - m), e1 = __expf(sc[tid + 256] - m);
  float s = e0 + e1;
  for (int d = 1; d < 64; d <<= 1) s += __shfl_xor(s, d);
  if ((tid & 63) == 0) red[4 + (tid >> 6)] = s;
  __syncthreads();
  s = red[4] + red[5] + red[6] + red[7];
  float inv = 1.f / s;
  at_l[tid] = e0 * inv;
  at_l[tid + 256] = e1 * inv;
  __syncthreads();

  // ---- weighted reduction: ct_d[b][kt*32..+32) ----
  int lane = tid & 63, w = tid >> 6;
  int kt = (blk & 7) * 4 + w;
  int lc = lane & 15, lr = lane >> 4;
  float a8[8] = {0.f, 0.f, 0.f, 0.f, 0.f, 0.f, 0.f, 0.f};
  const unsigned char* base =
      Aq + ((size_t)b * 1024 + kt) * 512 + (size_t)lane * 8;
  #pragma unroll 8
  for (int mt = 0; mt < 32; mt++) {
    float a = at_l[mt * 16 + lc];
    uint2 uv = *(const uint2*)(base + (size_t)mt * 16384);
    a8[0] += a * __builtin_amdgcn_cvt_f32_fp8(uv.x, 0);
    a8[1] += a * __builtin_amdgcn_cvt_f32_fp8(uv.x, 1);
    a8[2] += a * __builtin_amdgcn_cvt_f32_fp8(uv.x, 2);
    a8[3] += a * __builtin_amdgcn_cvt_f32_fp8(uv.x, 3);
    a8[4] += a * __builtin_amdgcn_cvt_f32_fp8(uv.y, 0);
    a8[5] += a * __builtin_amdgcn_cvt_f32_fp8(uv.y, 1);
    a8[6] += a * __builtin_amdgcn_cvt_f32_fp8(uv.y, 2);
    a8[7] += a * __builtin_amdgcn_cvt_f32_fp8(uv.y, 3);
  }
  #pragma unroll
  for (int d = 1; d < 16; d <<= 1)
    #pragma unroll
    for (int j = 0; j < 8; j++) a8[j] += __shfl_xor(a8[j], d);
  if (lc == 0) {
    #pragma unroll
    for (int j = 0; j < 8; j++)
      out[(size_t)b * H_DIM + kt * 32 + lr * 8 + j] = a8[j] * 0.25f;
  }
}

extern "C" void kernel_launch(void* const* d_in, const int* in_sizes, int n_in,
                              void* d_out, int out_size, void* d_ws, size_t ws_size,
                              hipStream_t stream) {
  (void)in_sizes; (void)n_in; (void)out_size; (void)ws_size;
  const float* s_t    = (const float*)d_in[0];
  const float* prev_s = (const float*)d_in[1];
  const float* W_prev = (const float*)d_in[2];
  const float* W_s    = (const float*)d_in[3];
  const float* b_s    = (const float*)d_in[4];
  const float* v      = (const float*)d_in[5];
  float* out = (float*)d_out;
  char* ws = (char*)d_ws;

  unsigned char* Aq = (unsigned char*)(ws + AQ8_OFF);
  unsigned char* Wq = (unsigned char*)(ws + BQ8_OFF);
  float* dec  = (float*)(ws + DEC_OFF);
  float* part = (float*)(ws + PART_OFF);

  prep_ws<<<2369, 256, 0, stream>>>(prev_s, s_t, W_prev, W_s, b_s, out, Aq, Wq, dec);
  score_gemm<<<2048, 256, 0, stream>>>(Aq, Wq, dec, v, part);
  ctd_ws<<<512, 256, 0, stream>>>(Aq, part, out);
}